// Round 12
// baseline (504.602 us; speedup 1.0000x reference)
//
#include <hip/hip_runtime.h>

#define B_ 2
#define L_ 2048
#define D_ 2048
#define H_ 8
#define HD_ 256
#define FD_ 64
#define F_ 128          // 2*FD
#define NC_ 32          // L/CHUNK
#define M_ (B_*L_)      // 4096
#define SCALE_Q 0.08838834764831845f   // 128^-0.5

typedef unsigned short u16;
typedef __attribute__((ext_vector_type(8))) short bf16x8;
typedef __attribute__((ext_vector_type(8))) unsigned short u16x8;
typedef __attribute__((ext_vector_type(4))) unsigned short u16x4;
typedef __attribute__((ext_vector_type(16))) float f32x16;
typedef __attribute__((ext_vector_type(4))) unsigned int u32x4;

// ---------------------------------------------------------------------------
// Tiled operand layouts (read-major: memory order == MFMA fragment order).
// 512-u16 chunk (one 32xK16 fragment set): addr = ((k>>3)&1)*256 + (x&31)*8
// + (k&7). Lane l reads u16x8 at chunk + l*8 -> (x = l&31, k = ks*16 +
// (l>>5)*8 + elem). Symmetric between A-frags and B-frags.
// ---------------------------------------------------------------------------

__device__ __forceinline__ u16 bf16_rne(float x) {
  unsigned u = __float_as_uint(x);
  return (u16)((u + 0x7fffu + ((u >> 16) & 1u)) >> 16);
}
__device__ __forceinline__ void bf16_split(float x, u16& h, u16& l) {
  unsigned u = __float_as_uint(x);
  unsigned hb = (u + 0x7fffu + ((u >> 16) & 1u)) >> 16;
  h = (u16)hb;
  float hf = __uint_as_float(hb << 16);
  l = bf16_rne(x - hf);
}

__device__ __forceinline__ void gl_lds16(const u16* g, u16* l) {
  __builtin_amdgcn_global_load_lds(
      (const __attribute__((address_space(1))) unsigned int*)g,
      (__attribute__((address_space(3))) unsigned int*)l, 16, 0, 0);
}

// kvb frag-tiled offset: per-chunk [2 d-panel][4 f-kt][4096] (F=128,HD=256).
__device__ __forceinline__ size_t kvb_off(int d, int f) {
  return (size_t)(((d >> 7) & 1) * 16384 + ((f >> 5) & 3) * 4096 +
                  ((d >> 6) & 1) * 2048 + ((f >> 4) & 1) * 1024 +
                  ((d >> 5) & 1) * 512 + ((f >> 3) & 1) * 256 +
                  (d & 31) * 8 + (f & 7));
}
// vb frag-tiled offset: per-chunk (J=64,HD=256) -> 16384 u16.
__device__ __forceinline__ size_t vb_off(int d, int j) {
  return (size_t)(((d >> 7) & 1) * 8192 + ((j >> 5) & 1) * 4096 +
                  ((d >> 6) & 1) * 2048 + ((j >> 4) & 1) * 1024 +
                  ((d >> 5) & 1) * 512 + ((j >> 3) & 1) * 256 +
                  (d & 31) * 8 + (j & 7));
}

// ---------------------------------------------------------------------------
// W[K=2048][Nsrc] fp32 -> B-tiled bf16 (panel P, ktile kt).
// ---------------------------------------------------------------------------
__device__ __forceinline__ void wtrans_body(const float* __restrict__ W, int Nsrc,
                                            int n0, u16* __restrict__ dst,
                                            int P, int kt) {
  int t = threadIdx.x;
  int nn = t & 127, kh = t >> 7;
  const float* src = W + (size_t)(kt * 32 + kh * 16) * Nsrc + n0 + nn;
  u16x8 u0, u1;
  #pragma unroll
  for (int kk = 0; kk < 8; ++kk) u0[kk] = bf16_rne(src[(size_t)kk * Nsrc]);
  #pragma unroll
  for (int kk = 0; kk < 8; ++kk) u1[kk] = bf16_rne(src[(size_t)(kk + 8) * Nsrc]);
  size_t base = ((size_t)P * 64 + kt) * 4096 + (size_t)((nn >> 6) & 1) * 2048
              + (size_t)kh * 1024 + (size_t)((nn >> 5) & 1) * 512
              + (size_t)(nn & 31) * 8;
  *(u16x8*)(dst + base) = u0;
  *(u16x8*)(dst + base + 256) = u1;
}

// Fused prep: hs split (0..4095) + Wq|Wk|Wv tiling (4096..5375) +
// fmq/fmk B-frag tiling (5376..5503) + (bigws) Wo tiling (5504..6527).
__global__ __launch_bounds__(256)
void prep_kernel(const float* __restrict__ hs,
                 const float* __restrict__ Wq, const float* __restrict__ Wk,
                 const float* __restrict__ Wv, const float* __restrict__ Wo,
                 const float* __restrict__ fmq, const float* __restrict__ fmk,
                 u16* __restrict__ hsHt, u16* __restrict__ hsLt,
                 u16* __restrict__ WTh, u16* __restrict__ WoTh,
                 u16* __restrict__ fmbtH, u16* __restrict__ fmbtL) {
  int bid = blockIdx.x;
  if (bid < 4096) {
    int gid = bid * 256 + threadIdx.x;
    int r = gid >> 8, u = gid & 255;
    const float* src = hs + (size_t)r * 2048 + u * 8;
    float4 v0 = *(const float4*)src, v1 = *(const float4*)(src + 4);
    float vals[8] = {v0.x, v0.y, v0.z, v0.w, v1.x, v1.y, v1.z, v1.w};
    u16x8 hv, lv;
    #pragma unroll
    for (int j = 0; j < 8; ++j) { u16 hh, ll; bf16_split(vals[j], hh, ll); hv[j] = hh; lv[j] = ll; }
    size_t off = ((size_t)(r >> 6) * 64 + (u >> 2)) * 2048
               + (size_t)((u >> 1) & 1) * 1024 + (size_t)((r >> 5) & 1) * 512
               + (size_t)(u & 1) * 256 + (size_t)(r & 31) * 8;
    *(u16x8*)(hsHt + off) = hv;
    *(u16x8*)(hsLt + off) = lv;
  } else if (bid < 5376) {
    int idx = bid - 4096;
    int P = idx >> 6, kt = idx & 63;
    const float* W; int Nsrc, n0;
    if (P < 16)      { W = Wq; Nsrc = 2048; n0 = P * 128; }
    else if (P < 18) { W = Wk; Nsrc = 256;  n0 = (P - 16) * 128; }
    else             { W = Wv; Nsrc = 256;  n0 = (P - 18) * 128; }
    wtrans_body(W, Nsrc, n0, WTh, P, kt);
  } else if (bid < 5504) {
    // fm B-frag tiling: per (h16, kt): 64 cols x 32 k -> 2048-u16 chunk.
    int idx = bid - 5376;                  // 0..127
    int h16 = idx >> 3, kt = idx & 7;
    const float* src = (h16 < 8) ? (fmq + (size_t)h16 * 16384)
                                 : (fmk + (size_t)(h16 - 8) * 16384);
    int t = threadIdx.x;
    int f = t & 63, kq = t >> 6;           // k = kq*8 + i
    u16x8 hv, lv;
    #pragma unroll
    for (int i = 0; i < 8; ++i) {
      float val = src[(size_t)(kt * 32 + kq * 8 + i) * 64 + f];
      u16 hh, ll; bf16_split(val, hh, ll); hv[i] = hh; lv[i] = ll;
    }
    size_t base = (size_t)(h16 * 8 + kt) * 2048 + (size_t)(kq >> 1) * 1024
                + (size_t)(f >> 5) * 512 + (size_t)(kq & 1) * 256
                + (size_t)(f & 31) * 8;
    *(u16x8*)(fmbtH + base) = hv;
    *(u16x8*)(fmbtL + base) = lv;
  } else {
    int idx = bid - 5504;
    wtrans_body(Wo, 2048, (idx >> 6) * 128, WoTh, idx >> 6, idx & 63);
  }
}

// Fallback standalone Wo tiling (small-workspace path).
__global__ __launch_bounds__(256)
void wtrans_wo(const float* __restrict__ Wo, u16* __restrict__ WoTh) {
  wtrans_body(Wo, 2048, blockIdx.x * 128, WoTh, blockIdx.x, blockIdx.y);
}

// Standalone prep_v (fallback path; bigws fuses into mfma_hh).
__global__ __launch_bounds__(256)
void prep_v(const float* __restrict__ v, u16* __restrict__ vbH,
            u16* __restrict__ vbL) {
  int bn = blockIdx.x;
  const float* vp = v + (size_t)bn * 64 * HD_;
  size_t cbout = (size_t)bn * 16384;
  int d = threadIdx.x;
  #pragma unroll
  for (int it = 0; it < 8; ++it) {
    int j0 = it * 8;
    u16x8 hv, lv;
    #pragma unroll
    for (int c = 0; c < 8; ++c) {
      u16 hh, ll; bf16_split(vp[(size_t)(j0 + c) * HD_ + d], hh, ll);
      hv[c] = hh; lv[c] = ll;
    }
    size_t off = cbout + vb_off(d, j0);
    *(u16x8*)(vbH + off) = hv;
    *(u16x8*)(vbL + off) = lv;
  }
}

// ---------------------------------------------------------------------------
// OLD 2-pass split-bf16 MFMA GEMM (64x128 tile, BK=32, 128 threads).
// Kept for the small k/v projection (full 256-block grid; R6-verified).
// ---------------------------------------------------------------------------
__device__ __forceinline__ void mfma_body(
    const u16* __restrict__ AtH, const u16* __restrict__ AtL,
    const u16* __restrict__ Bt, float* __restrict__ C, int cstride,
    int bm, int bn) {
  __shared__ __align__(16) u16 AsH[2048];
  __shared__ __align__(16) u16 AsL[2048];
  __shared__ __align__(16) u16 Bs[4096];
  const int t = threadIdx.x, lane = t & 63, wv = t >> 6;
  const u16* aSrc = (wv ? AtL : AtH) + (size_t)bm * 131072 + lane * 8;
  const u16* bSrc = Bt + (size_t)bn * 262144 + wv * 2048 + lane * 8;
  u16* aDst = wv ? AsL : AsH;
  u16* bDst = Bs + wv * 2048;

  f32x16 acc[2][2];
  #pragma unroll
  for (int a = 0; a < 2; ++a)
    #pragma unroll
    for (int b2 = 0; b2 < 2; ++b2)
      #pragma unroll
      for (int r = 0; r < 16; ++r) acc[a][b2][r] = 0.f;

  for (int kt = 0; kt < 64; ++kt) {
    const u16* ak = aSrc + (size_t)kt * 2048;
    const u16* bk = bSrc + (size_t)kt * 4096;
    __syncthreads();
    #pragma unroll
    for (int c = 0; c < 4; ++c) {
      gl_lds16(ak + c * 512, aDst + c * 512);
      gl_lds16(bk + c * 512, bDst + c * 512);
    }
    __syncthreads();

    #pragma unroll
    for (int ks = 0; ks < 2; ++ks) {
      const u16* ph = AsH + ks * 1024 + lane * 8;
      const u16* pl = AsL + ks * 1024 + lane * 8;
      const u16* pb = Bs + wv * 2048 + ks * 1024 + lane * 8;
      bf16x8 a0 = *(const bf16x8*)ph;
      bf16x8 a1 = *(const bf16x8*)(ph + 512);
      bf16x8 b0 = *(const bf16x8*)pb;
      bf16x8 b1 = *(const bf16x8*)(pb + 512);
      acc[0][0] = __builtin_amdgcn_mfma_f32_32x32x16_bf16(a0, b0, acc[0][0], 0, 0, 0);
      acc[0][1] = __builtin_amdgcn_mfma_f32_32x32x16_bf16(a0, b1, acc[0][1], 0, 0, 0);
      acc[1][0] = __builtin_amdgcn_mfma_f32_32x32x16_bf16(a1, b0, acc[1][0], 0, 0, 0);
      acc[1][1] = __builtin_amdgcn_mfma_f32_32x32x16_bf16(a1, b1, acc[1][1], 0, 0, 0);
      bf16x8 l0 = *(const bf16x8*)pl;
      bf16x8 l1 = *(const bf16x8*)(pl + 512);
      acc[0][0] = __builtin_amdgcn_mfma_f32_32x32x16_bf16(l0, b0, acc[0][0], 0, 0, 0);
      acc[0][1] = __builtin_amdgcn_mfma_f32_32x32x16_bf16(l0, b1, acc[0][1], 0, 0, 0);
      acc[1][0] = __builtin_amdgcn_mfma_f32_32x32x16_bf16(l1, b0, acc[1][0], 0, 0, 0);
      acc[1][1] = __builtin_amdgcn_mfma_f32_32x32x16_bf16(l1, b1, acc[1][1], 0, 0, 0);
    }
  }

  const int fr = lane & 31, g = lane >> 5;
  float* Cp = C + (size_t)(bm * 64) * cstride + wv * 64;
  #pragma unroll
  for (int mt = 0; mt < 2; ++mt)
    #pragma unroll
    for (int nt = 0; nt < 2; ++nt) {
      #pragma unroll
      for (int r = 0; r < 16; ++r) {
        int row = mt * 32 + (r & 3) + 8 * (r >> 2) + 4 * g;
        Cp[(size_t)row * cstride + nt * 32 + fr] = acc[mt][nt][r];
      }
    }
}

// ---------------------------------------------------------------------------
// Pipelined body v3: 128x128 tile, 4 waves, BK=32, triple ring (72 KB ->
// 2 blocks/CU), phase-split + counted vmcnt(6) + setprio. (R9: 68us, 44%.)
// ---------------------------------------------------------------------------
#define SUB_ 12288
#define MFB(a_, b_, c_) (c_) = __builtin_amdgcn_mfma_f32_32x32x16_bf16((a_), (b_), (c_), 0, 0, 0)

__device__ __forceinline__ void mfma_big_body(
    const u16* __restrict__ AtH, const u16* __restrict__ AtL,
    const u16* __restrict__ Bt, float* __restrict__ C, int cstride,
    int bm, int bn) {
  __shared__ __align__(16) u16 lds[3 * SUB_];
  const int t = threadIdx.x, lane = t & 63, wv = t >> 6;
  const int wm = wv >> 1, wn = wv & 1;

  const u16* gs[6];
  unsigned lo[6], gst[6];
  #pragma unroll
  for (int j = 0; j < 6; ++j) {
    int line = wv * 6 + j;
    if (line < 8) {
      gs[j] = AtH + ((size_t)(2 * bm + (line >> 2)) * 64) * 2048
                  + (size_t)(line & 3) * 512 + lane * 8;
      gst[j] = 2048;
    } else if (line < 16) {
      int l2 = line - 8;
      gs[j] = AtL + ((size_t)(2 * bm + (l2 >> 2)) * 64) * 2048
                  + (size_t)(l2 & 3) * 512 + lane * 8;
      gst[j] = 2048;
    } else {
      int l3 = line - 16;
      gs[j] = Bt + (size_t)bn * 262144 + (size_t)l3 * 512 + lane * 8;
      gst[j] = 4096;
    }
    lo[j] = line * 512;
  }

  f32x16 acc[2][2];
  #pragma unroll
  for (int a = 0; a < 2; ++a)
    #pragma unroll
    for (int b2 = 0; b2 < 2; ++b2)
      #pragma unroll
      for (int r = 0; r < 16; ++r) acc[a][b2][r] = 0.f;

  #pragma unroll
  for (int j = 0; j < 6; ++j) gl_lds16(gs[j], lds + lo[j]);
  #pragma unroll
  for (int j = 0; j < 6; ++j) gl_lds16(gs[j] + gst[j], lds + SUB_ + lo[j]);
  asm volatile("s_waitcnt vmcnt(6)" ::: "memory");
  __builtin_amdgcn_s_barrier();
  __builtin_amdgcn_sched_barrier(0);

  int cb = 0;
  for (int kt = 0; kt < 64; ++kt) {
    int sb = cb + 2 * SUB_; if (sb >= 3 * SUB_) sb -= 3 * SUB_;
    const u16* base = lds + cb;
    const u16* ph0 = base + wm * 2048 + lane * 8;
    const u16* pb0 = base + 8192 + wn * 2048 + lane * 8;

    bf16x8 a0 = *(const bf16x8*)(ph0);
    bf16x8 a1 = *(const bf16x8*)(ph0 + 512);
    bf16x8 l0 = *(const bf16x8*)(ph0 + 4096);
    bf16x8 l1 = *(const bf16x8*)(ph0 + 4608);
    bf16x8 b0 = *(const bf16x8*)(pb0);
    bf16x8 b1 = *(const bf16x8*)(pb0 + 512);
    if (kt < 62) {
      gl_lds16(gs[0] + (size_t)(kt + 2) * gst[0], lds + sb + lo[0]);
      gl_lds16(gs[1] + (size_t)(kt + 2) * gst[1], lds + sb + lo[1]);
      gl_lds16(gs[2] + (size_t)(kt + 2) * gst[2], lds + sb + lo[2]);
    }
    __builtin_amdgcn_s_barrier();
    asm volatile("s_waitcnt lgkmcnt(0)" ::: "memory");
    __builtin_amdgcn_sched_barrier(0);
    __builtin_amdgcn_s_setprio(1);
    MFB(a0, b0, acc[0][0]); MFB(a0, b1, acc[0][1]);
    MFB(a1, b0, acc[1][0]); MFB(a1, b1, acc[1][1]);
    MFB(l0, b0, acc[0][0]); MFB(l0, b1, acc[0][1]);
    MFB(l1, b0, acc[1][0]); MFB(l1, b1, acc[1][1]);
    __builtin_amdgcn_s_setprio(0);
    __builtin_amdgcn_s_barrier();
    __builtin_amdgcn_sched_barrier(0);

    bf16x8 c0 = *(const bf16x8*)(ph0 + 1024);
    bf16x8 c1 = *(const bf16x8*)(ph0 + 1536);
    bf16x8 m0 = *(const bf16x8*)(ph0 + 5120);
    bf16x8 m1 = *(const bf16x8*)(ph0 + 5632);
    bf16x8 d0 = *(const bf16x8*)(pb0 + 1024);
    bf16x8 d1 = *(const bf16x8*)(pb0 + 1536);
    if (kt < 62) {
      gl_lds16(gs[3] + (size_t)(kt + 2) * gst[3], lds + sb + lo[3]);
      gl_lds16(gs[4] + (size_t)(kt + 2) * gst[4], lds + sb + lo[4]);
      gl_lds16(gs[5] + (size_t)(kt + 2) * gst[5], lds + sb + lo[5]);
    }
    __builtin_amdgcn_s_barrier();
    asm volatile("s_waitcnt lgkmcnt(0)" ::: "memory");
    __builtin_amdgcn_sched_barrier(0);
    __builtin_amdgcn_s_setprio(1);
    MFB(c0, d0, acc[0][0]); MFB(c0, d1, acc[0][1]);
    MFB(c1, d0, acc[1][0]); MFB(c1, d1, acc[1][1]);
    MFB(m0, d0, acc[0][0]); MFB(m0, d1, acc[0][1]);
    MFB(m1, d0, acc[1][0]); MFB(m1, d1, acc[1][1]);
    __builtin_amdgcn_s_setprio(0);
    if (kt < 62) asm volatile("s_waitcnt vmcnt(6)" ::: "memory");
    else         asm volatile("s_waitcnt vmcnt(0)" ::: "memory");
    __builtin_amdgcn_s_barrier();
    __builtin_amdgcn_sched_barrier(0);
    cb += SUB_; if (cb == 3 * SUB_) cb = 0;
  }

  const int fr = lane & 31, g = lane >> 5;
  float* Cp = C + (size_t)(bm * 128 + wm * 64) * cstride + wn * 64;
  #pragma unroll
  for (int mt = 0; mt < 2; ++mt)
    #pragma unroll
    for (int nt = 0; nt < 2; ++nt) {
      #pragma unroll
      for (int r = 0; r < 16; ++r) {
        int row = mt * 32 + (r & 3) + 8 * (r >> 2) + 4 * g;
        Cp[(size_t)row * cstride + nt * 32 + fr] = acc[mt][nt][r];
      }
    }
}

// q projection: grid (16,32) = 512 blocks = exactly 2/CU (R9-verified).
__global__ __launch_bounds__(256, 2)
void mfma_q(const u16* __restrict__ hsHt, const u16* __restrict__ hsLt,
            const u16* __restrict__ WTh, float* __restrict__ q) {
  mfma_big_body(hsHt, hsLt, WTh, q + blockIdx.x * 128, 2048,
                blockIdx.y, blockIdx.x);
}

// k/v projections: old body, grid (4,64) = 256 blocks (R6-verified).
__global__ __launch_bounds__(128, 4)
void mfma_kv(const u16* __restrict__ hsHt, const u16* __restrict__ hsLt,
             const u16* __restrict__ WTh,
             float* __restrict__ k, float* __restrict__ v) {
  int bn = blockIdx.x;
  float* Cb; int co;
  if (bn < 2) { Cb = k; co = bn * 128; }
  else        { Cb = v; co = (bn - 2) * 128; }
  mfma_body(hsHt, hsLt, WTh, Cb + co, 256, blockIdx.y, 16 + bn);
}

__global__ __launch_bounds__(256, 2)
void mfma_wo(const u16* __restrict__ oHt, const u16* __restrict__ oLt,
             const u16* __restrict__ WoTh, float* __restrict__ out) {
  mfma_big_body(oHt, oLt, WoTh, out + blockIdx.x * 128, 2048,
                blockIdx.y, blockIdx.x);
}

// ---------------------------------------------------------------------------
// mfma_hh: RoPE + hedgehog projection via MFMA. (R9-verified.)
// ---------------------------------------------------------------------------
__global__ __launch_bounds__(256, 1)
void mfma_hh(const float* __restrict__ q, const float* __restrict__ kx,
             const float* __restrict__ cosb, const float* __restrict__ sinb,
             const u16* __restrict__ fmbtH, const u16* __restrict__ fmbtL,
             float* __restrict__ qf, float* __restrict__ kf,
             const float* __restrict__ vsrc,
             u16* __restrict__ vbH, u16* __restrict__ vbL) {
  int bid = blockIdx.x;
  if (bid >= 512) {                     // fused prep_v (bigws path)
    int bn = bid - 512;
    const float* vp = vsrc + (size_t)bn * 64 * HD_;
    size_t cbout = (size_t)bn * 16384;
    int d = threadIdx.x;
    #pragma unroll
    for (int it = 0; it < 8; ++it) {
      int j0 = it * 8;
      u16x8 hv, lv;
      #pragma unroll
      for (int c = 0; c < 8; ++c) {
        u16 hh, ll; bf16_split(vp[(size_t)(j0 + c) * HD_ + d], hh, ll);
        hv[c] = hh; lv[c] = ll;
      }
      size_t off = cbout + vb_off(d, j0);
      *(u16x8*)(vbH + off) = hv;
      *(u16x8*)(vbL + off) = lv;
    }
    return;
  }
  __shared__ __align__(16) u16 xlds[65536];   // [kt][rt32][hl][1024]
  const int t = threadIdx.x;
  const int rt = bid & 31, h16 = bid >> 5;
  const int rowbase = rt * 128;
  const float* xsrc; size_t xstr;
  if (h16 < 8) { xsrc = q + (size_t)h16 * 256; xstr = 2048; }
  else         { xsrc = kx;                    xstr = 256; }

  // ---- stage: RoPE + split -> A-frag LDS ----
  for (int iter = 0; iter < 16; ++iter) {
    int flat = iter * 1024 + t * 4;          // 128 rows x 128 dd
    int r = flat >> 7, dd = flat & 127;
    int grow = rowbase + r;
    int l = grow & 2047;
    const float* xr = xsrc + (size_t)grow * xstr + dd;
    float4 x1 = *(const float4*)xr;
    float4 x2 = *(const float4*)(xr + 128);
    float4 c  = *(const float4*)(cosb + (size_t)l * 128 + dd);
    float4 s  = *(const float4*)(sinb + (size_t)l * 128 + dd);
    float lo4[4] = {x1.x*c.x - x2.x*s.x, x1.y*c.y - x2.y*s.y,
                    x1.z*c.z - x2.z*s.z, x1.w*c.w - x2.w*s.w};
    float hi4[4] = {x1.x*s.x + x2.x*c.x, x1.y*s.y + x2.y*c.y,
                    x1.z*s.z + x2.z*c.z, x1.w*s.w + x2.w*c.w};
    int rt32 = r >> 5, r5 = r & 31;
    #pragma unroll
    for (int half = 0; half < 2; ++half) {
      int d = dd + half * 128;
      int kt = d >> 5, k = d & 31;
      unsigned base = (unsigned)((kt * 4 + rt32) * 2) * 1024
                    + (unsigned)(k >> 4) * 512 + (unsigned)((k >> 3) & 1) * 256
                    + (unsigned)r5 * 8 + (unsigned)(k & 7);
      const float* vv = half ? hi4 : lo4;
      u16x4 hv, lv;
      #pragma unroll
      for (int j = 0; j < 4; ++j) {
        u16 hh, ll; bf16_split(vv[j], hh, ll); hv[j] = hh; lv[j] = ll;
      }
      *(u16x4*)(xlds + base) = hv;
      *(u16x4*)(xlds + 1024 + base) = lv;
    }
  }
  __syncthreads();

  // ---- MFMA: wave w = rowtile, both nt; 3-pass split ----
  const int w = t >> 6, lane = t & 63;
  f32x16 acc[2];
  #pragma unroll
  for (int nt = 0; nt < 2; ++nt)
    #pragma unroll
    for (int r = 0; r < 16; ++r) acc[nt][r] = 0.f;

  const u16* fmbH = fmbtH + (size_t)h16 * 8 * 2048;
  const u16* fmbL = fmbtL + (size_t)h16 * 8 * 2048;
  #pragma unroll
  for (int kt = 0; kt < 8; ++kt) {
    unsigned xb = (unsigned)((kt * 4 + w) * 2) * 1024;
    #pragma unroll
    for (int ks = 0; ks < 2; ++ks) {
      bf16x8 xh = *(const bf16x8*)(xlds + xb + ks * 512 + lane * 8);
      bf16x8 xl = *(const bf16x8*)(xlds + xb + 1024 + ks * 512 + lane * 8);
      #pragma unroll
      for (int nt = 0; nt < 2; ++nt) {
        size_t fb = (size_t)kt * 2048 + ks * 1024 + nt * 512 + lane * 8;
        bf16x8 bh_ = *(const bf16x8*)((const short*)(fmbH + fb));
        bf16x8 bl_ = *(const bf16x8*)((const short*)(fmbL + fb));
        MFB(xh, bh_, acc[nt]); MFB(xl, bh_, acc[nt]); MFB(xh, bl_, acc[nt]);
      }
    }
  }

  // ---- softmax over concat(p,-p) + store qf/kf ----
  const int g = lane >> 5, f31 = lane & 31;
  float* outp = (h16 < 8) ? qf : kf;
  const int hh = h16 & 7;
  #pragma unroll
  for (int r = 0; r < 16; ++r) {
    int rowl = (r & 3) + 8 * (r >> 2) + 4 * g;
    int grow = rowbase + w * 32 + rowl;
    float p0 = acc[0][r], p1 = acc[1][r];
    float m = fmaxf(fabsf(p0), fabsf(p1));
    #pragma unroll
    for (int off = 16; off > 0; off >>= 1) m = fmaxf(m, __shfl_xor(m, off, 64));
    float e0 = __expf(p0 - m),  e0n = __expf(-p0 - m);
    float e1 = __expf(p1 - m),  e1n = __expf(-p1 - m);
    float zl = e0 + e0n + e1 + e1n;
    #pragma unroll
    for (int off = 16; off > 0; off >>= 1) zl += __shfl_xor(zl, off, 64);
    float inv = 1.0f / zl;
    int b = grow >> 11, l = grow & 2047;
    size_t ob = ((size_t)((b * 8 + hh) * 2048 + l)) * 128;
    outp[ob + f31]       = e0 * inv;
    outp[ob + 32 + f31]  = e1 * inv;
    outp[ob + 64 + f31]  = e0n * inv;
    outp[ob + 96 + f31]  = e1n * inv;
  }
}

// ---------------------------------------------------------------------------
// Fused chunk_kv + scan: fp32 running prefix in registers, exclusive prefix
// written split-bf16 directly. (R10-introduced; isolated read this round.)
// ---------------------------------------------------------------------------
__global__ __launch_bounds__(256)
void chunk_kvscan_kernel(const float* __restrict__ kf, const float* __restrict__ v,
                         u16* __restrict__ kvbH, u16* __restrict__ kvbL) {
  __shared__ __align__(16) float kfs[64][8];
  int bh = blockIdx.x >> 4, g = blockIdx.x & 15;
  int b = bh >> 3;
  int f0 = g * 8;
  int d = threadIdx.x;
  size_t off = kvb_off(d, f0);
  const float* kfb = kf + (size_t)bh * L_ * F_ + f0;
  const float* vb_ = v + (size_t)b * L_ * HD_ + d;
  float run[8] = {0.f, 0.f, 0.f, 0.f, 0.f, 0.f, 0.f, 0.f};
  for (int n = 0; n < NC_; ++n) {
    // write exclusive prefix for chunk n
    u16x8 oh, ol;
    #pragma unroll
    for (int c = 0; c < 8; ++c) {
      u16 hh, ll; bf16_split(run[c], hh, ll); oh[c] = hh; ol[c] = ll;
    }
    size_t a = ((size_t)(bh * 32 + n)) * 32768 + off;
    *(u16x8*)(kvbH + a) = oh;
    *(u16x8*)(kvbL + a) = ol;
    // load kf slice for chunk n (prev readers done before overwrite)
    __syncthreads();
    if (threadIdx.x < 128) {
      int flat = threadIdx.x * 4;          // 512 floats: 64 j x 8 f
      int j = flat >> 3, f = flat & 7;
      *(float4*)&kfs[j][f] =
          *(const float4*)(kfb + (size_t)(n * 64 + j) * F_ + f);
    }
    __syncthreads();
    // accumulate chunk n into the running sum
    const float* vp = vb_ + (size_t)n * 64 * HD_;
    for (int j = 0; j < 64; ++j) {
      float vv = vp[(size_t)j * HD_];
      #pragma unroll
      for (int c = 0; c < 8; ++c) run[c] += kfs[j][c] * vv;
    }
  }
}

// ---------------------------------------------------------------------------
// Phase C (MFMA): epilogue writes A-tiled split bf16 oHt/oLt directly.
// ---------------------------------------------------------------------------
__global__ __launch_bounds__(256, 2)
void chunk_attn_kernel(const float* __restrict__ qf, const float* __restrict__ kf,
                       const u16* __restrict__ vbH, const u16* __restrict__ vbL,
                       const u16* __restrict__ kvbH, const u16* __restrict__ kvbL,
                       u16* __restrict__ oHt, u16* __restrict__ oLt) {
  __shared__ __align__(16) u16 lds[32768];   // qsH|qsL|kfH|kfL
  const int n = blockIdx.x & (NC_ - 1), bh = blockIdx.x >> 5;
  const int h = bh & 7, b = bh >> 3;
  const int t = threadIdx.x;
  const int w = t >> 6, i31 = t & 31, G = (t >> 5) & 1;
  const int l8 = (t & 63) * 8;

  {
    const float* qp = qf + ((size_t)bh * L_ + (size_t)n * 64) * F_;
    const float* kp = kf + ((size_t)bh * L_ + (size_t)n * 64) * F_;
    int o8 = t & 15, ib = t >> 4;
    #pragma unroll
    for (int iter = 0; iter < 4; ++iter) {
      int i = ib + iter * 16;
      int it = i >> 5, ks = o8 >> 1;
      int sub = (it * 8 + ks) * 512 + (o8 & 1) * 256 + (i & 31) * 8;
      {
        const float* src = qp + (size_t)i * 128 + o8 * 8;
        float4 a = *(const float4*)src, c = *(const float4*)(src + 4);
        float vals[8] = {a.x, a.y, a.z, a.w, c.x, c.y, c.z, c.w};
        u16x8 hv, lv;
        #pragma unroll
        for (int j = 0; j < 8; ++j) {
          u16 hh, ll; bf16_split(vals[j] * SCALE_Q, hh, ll);
          hv[j] = hh; lv[j] = ll;
        }
        *(u16x8*)(lds + sub) = hv;
        *(u16x8*)(lds + 8192 + sub) = lv;
      }
      {
        const float* src = kp + (size_t)i * 128 + o8 * 8;
        float4 a = *(const float4*)src, c = *(const float4*)(src + 4);
        float vals[8] = {a.x, a.y, a.z, a.w, c.x, c.y, c.z, c.w};
        u16x8 hv, lv;
        #pragma unroll
        for (int j = 0; j < 8; ++j) {
          u16 hh, ll; bf16_split(vals[j], hh, ll);
          hv[j] = hh; lv[j] = ll;
        }
        *(u16x8*)(lds + 16384 + sub) = hv;
        *(u16x8*)(lds + 24576 + sub) = lv;
      }
    }
  }
  __syncthreads();

  const u16* Lq  = lds;
  const u16* Lql = lds + 8192;
  const u16* Lk  = lds + 16384;
  const u16* Lkl = lds + 24576;

  // ---- phase S: sT = kf · qs^T (3-pass split) ----
  f32x16 st[2][2];
  #pragma unroll
  for (int a = 0; a < 2; ++a)
    #pragma unroll
    for (int c = 0; c < 2; ++c)
      #pragma unroll
      for (int r = 0; r < 16; ++r) st[a][c][r] = 0.f;

  #pragma unroll
  for (int ks = 0; ks < 8; ++ks) {
    bf16x8 kh0 = *(const bf16x8*)(Lk  + ks * 512 + l8);
    bf16x8 kh1 = *(const bf16x8*)(Lk  + (8 + ks) * 512 + l8);
    bf16x8 kl0 = *(const bf16x8*)(Lkl + ks * 512 + l8);
    bf16x8 kl1 = *(const bf16x8*)(Lkl + (8 + ks) * 512 + l8);
    bf16x8 qh0 = *(const bf16x8*)(Lq  + ks * 512 + l8);
    bf16x8 qh1 = *(const bf16x8*)(Lq  + (8 + ks) * 512 + l8);
    bf16x8 ql0 = *(const bf16x8*)(Lql + ks * 512 + l8);
    bf16x8 ql1 = *(const bf16x8*)(Lql + (8 + ks) * 512 + l8);
    MFB(kh0, qh0, st[0][0]); MFB(kh0, ql0, st[0][0]); MFB(kl0, qh0, st[0][0]);
    MFB(kh0, qh1, st[0][1]); MFB(kh0, ql1, st[0][1]); MFB(kl0, qh1, st[0][1]);
    MFB(kh1, qh0, st[1][0]); MFB(kh1, ql0, st[1][0]); MFB(kl1, qh0, st[1][0]);
    MFB(kh1, qh1, st[1][1]); MFB(kh1, ql1, st[1][1]); MFB(kl1, qh1, st[1][1]);
  }

  // ---- mask + split + cross-lane transpose: sT C-regs -> s A-frags ----
  bf16x8 sfH[2][4], sfL[2][4];
  #pragma unroll
  for (int mt = 0; mt < 2; ++mt) {
    int iv = mt * 32 + i31;
    #pragma unroll
    for (int ksj = 0; ksj < 4; ++ksj) {
      const int jt = ksj >> 1, kb = ksj & 1;
      unsigned ph[4], pl[4];
      #pragma unroll
      for (int half = 0; half < 2; ++half) {
        u16 hh[4], ll[4];
        #pragma unroll
        for (int c = 0; c < 4; ++c) {
          int r = 8 * kb + 4 * half + c;
          int jv = jt * 32 + (r & 3) + 8 * (r >> 2) + 4 * G;
          float mv = (jv <= iv) ? st[jt][mt][r] : 0.f;
          u16 h_, l_; bf16_split(mv, h_, l_);
          hh[c] = h_; ll[c] = l_;
        }
        ph[half * 2 + 0] = (unsigned)hh[0] | ((unsigned)hh[1] << 16);
        ph[half * 2 + 1] = (unsigned)hh[2] | ((unsigned)hh[3] << 16);
        pl[half * 2 + 0] = (unsigned)ll[0] | ((unsigned)ll[1] << 16);
        pl[half * 2 + 1] = (unsigned)ll[2] | ((unsigned)ll[3] << 16);
      }
      unsigned rH1 = (unsigned)__shfl_xor((int)(G ? ph[0] : ph[2]), 32, 64);
      unsigned rH2 = (unsigned)__shfl_xor((int)(G ? ph[1] : ph[3]), 32, 64);
      unsigned rL1 = (unsigned)__shfl_xor((int)(G ? pl[0] : pl[2]), 32, 64);
      unsigned rL2 = (unsigned)__shfl_xor((int)(G ? pl[1] : pl[3]), 32, 64);
      u32x4 wH, wL;
      wH[0] = G ? rH1 : ph[0]; wH[1] = G ? rH2 : ph[1];
      wH[2] = G ? ph[2] : rH1; wH[3] = G ? ph[3] : rH2;
      wL[0] = G ? rL1 : pl[0]; wL[1] = G ? rL2 : pl[1];
      wL[2] = G ? pl[2] : rL1; wL[3] = G ? pl[3] : rL2;
      sfH[mt][ksj] = __builtin_bit_cast(bf16x8, wH);
      sfL[mt][ksj] = __builtin_bit_cast(bf16x8, wL);
    }
  }

  f32x16 acc[2][2];
  #pragma unroll
  for (int a = 0; a < 2; ++a)
    #pragma unroll
    for (int c = 0; c < 2; ++c)
      #pragma unroll
      for (int r = 0; r < 16; ++r) acc[a][c][r] = 0.f;

  // ---- phase A (intra): acc += s · v, v frags pre-tiled ----
  {
    size_t vcb = ((size_t)(b * NC_ + n)) * 16384;
    #pragma unroll
    for (int nt = 0; nt < 2; ++nt) {
      #pragma unroll
      for (int ksj = 0; ksj < 4; ++ksj) {
        size_t basev = vcb + vb_off(w * 64 + nt * 32, ksj * 16) + l8;
        bf16x8 vH = *(const bf16x8*)((const short*)(vbH + basev));
        bf16x8 vL = *(const bf16x8*)((const short*)(vbL + basev));
        MFB(sfH[0][ksj], vH, acc[0][nt]); MFB(sfL[0][ksj], vH, acc[0][nt]);
        MFB(sfH[0][ksj], vL, acc[0][nt]);
        MFB(sfH[1][ksj], vH, acc[1][nt]); MFB(sfL[1][ksj], vH, acc[1][nt]);
        MFB(sfH[1][ksj], vL, acc[1][nt]);
      }
    }
  }

  // ---- phase I (inter): acc += qs · kv_cum ----
  {
    size_t cb = (size_t)blockIdx.x * 32768;
    #pragma unroll
    for (int ks = 0; ks < 8; ++ks) {
      bf16x8 qa_h0 = *(const bf16x8*)(Lq  + ks * 512 + l8);
      bf16x8 qa_h1 = *(const bf16x8*)(Lq  + (8 + ks) * 512 + l8);
      bf16x8 qa_l0 = *(const bf16x8*)(Lql + ks * 512 + l8);
      bf16x8 qa_l1 = *(const bf16x8*)(Lql + (8 + ks) * 512 + l8);
      #pragma unroll
      for (int nt = 0; nt < 2; ++nt) {
        size_t base = cb + kvb_off(w * 64 + nt * 32, ks * 16) + l8;
        bf16x8 kvH = *(const bf16x8*)((const short*)(kvbH + base));
        bf16x8 kvL = *(const bf16x8*)((const short*)(kvbL + base));
        MFB(qa_h0, kvH, acc[0][nt]); MFB(qa_l0, kvH, acc[0][nt]);
        MFB(qa_h0, kvL, acc[0][nt]);
        MFB(qa_h1, kvH, acc[1][nt]); MFB(qa_l1, kvH, acc[1][nt]);
        MFB(qa_h1, kvL, acc[1][nt]);
      }
    }
  }

  // ---- fused epilogue: A-tiled split bf16 write ----
  {
    int p = b * NC_ + n;
    #pragma unroll
    for (int mt = 0; mt < 2; ++mt)
      #pragma unroll
      for (int nt = 0; nt < 2; ++nt) {
        int u_ = h * 32 + w * 8 + nt * 4 + (i31 >> 3);
        size_t ob = ((size_t)p * 64 + (u_ >> 2)) * 2048
                  + (size_t)((u_ >> 1) & 1) * 1024 + (size_t)mt * 512
                  + (size_t)(u_ & 1) * 256 + (size_t)(i31 & 7);
        #pragma unroll
        for (int r = 0; r < 16; ++r) {
          int rr = (r & 3) + 8 * (r >> 2) + 4 * G;
          u16 hh, ll; bf16_split(acc[mt][nt][r], hh, ll);
          oHt[ob + (size_t)rr * 8] = hh;
          oLt[ob + (size_t)rr * 8] = ll;
        }
      }
  }
}

// ---------------------------------------------------------------------------
extern "C" void kernel_launch(void* const* d_in, const int* in_sizes, int n_in,
                              void* d_out, int out_size, void* d_ws, size_t ws_size,
                              hipStream_t stream) {
  const float* hs   = (const float*)d_in[0];
  const float* fcos = (const float*)d_in[1];
  const float* fsin = (const float*)d_in[2];
  // d_in[3] = mask (all ones, unused)
  const float* Wq  = (const float*)d_in[4];
  const float* Wk  = (const float*)d_in[5];
  const float* Wv  = (const float*)d_in[6];
  const float* Wo  = (const float*)d_in[7];
  const float* fmq = (const float*)d_in[8];
  const float* fmk = (const float*)d_in[9];
  float* out = (float*)d_out;

  float* ws = (float*)d_ws;
  float* q  = ws;                                   // 32MB; later oHt/oLt
  float* k  = q  + (size_t)M_ * 2048;               // 4MB; (!bigws: vb tiles)
  float* v  = k  + (size_t)M_ * 256;                // 4MB
  float* qf = v  + (size_t)M_ * 256;                // 16MB
  float* kf = qf + (size_t)B_ * H_ * L_ * F_;       // 16MB
  float* kvr = kf + (size_t)B_ * H_ * L_ * F_;      // 64MB region

  u16* hsHt = (u16*)kvr;                      // 16 MB
  u16* hsLt = hsHt + (size_t)M_ * 2048;       // 16 MB
  u16* WTh  = hsLt + (size_t)M_ * 2048;       // 10 MB
  // fm B-frag tiles in the dead tail of kvr (live until mfma_hh; kvb
  // overwrites kvr only later, in chunk_kvscan).
  u16* fmbtH = WTh + (size_t)1280 * 4096;     // 0.5 MB
  u16* fmbtL = fmbtH + (size_t)131072 * 2;    // 0.5 MB
  u16* kvbH = (u16*)kvr;                      // 32 MB
  u16* kvbL = kvbH + (size_t)512 * 32768;     // 32 MB
  u16* oHt  = (u16*)q;                        // 16 MB (q dead after mfma_hh)
  u16* oLt  = oHt + (size_t)M_ * 2048;        // 16 MB

  // bigws extras past the 136 MB base: WoTh (8 MB) + vb tiles (4 MB).
  const size_t WS_BASE = (size_t)142606336;   // 136 MB
  bool bigws = ws_size >= WS_BASE + (size_t)12582912;
  u16* WoTh = bigws ? (u16*)((char*)d_ws + WS_BASE) : (u16*)kvr;
  u16* vbH  = bigws ? (u16*)((char*)d_ws + WS_BASE + 8388608) : (u16*)k;
  u16* vbL  = vbH + (size_t)64 * 16384;

  // 1) Fused prep: hs split + Wq/Wk/Wv tiling + fm tiling (+ Wo when bigws)
  prep_kernel<<<bigws ? 6528 : 5504, 256, 0, stream>>>(
      hs, Wq, Wk, Wv, Wo, fmq, fmk, hsHt, hsLt, WTh, WoTh, fmbtH, fmbtL);
  // 2a) q projection: pipelined body, grid (16,32) = 512 blocks = 2/CU exact
  mfma_q<<<dim3(16, 32), 256, 0, stream>>>(hsHt, hsLt, WTh, q);
  // 2b) k/v projections: old body, 256 blocks (reverted R10 tail-quantized fusion)
  mfma_kv<<<dim3(4, 64), 128, 0, stream>>>(hsHt, hsLt, WTh, k, v);
  // 3) MFMA RoPE+hedgehog; bigws fuses prep_v
  mfma_hh<<<bigws ? 576 : 512, 256, 0, stream>>>(
      q, k, fcos, fsin, fmbtH, fmbtL, qf, kf, v, vbH, vbL);
  // 3b) fallback prep_v AFTER mfma_hh (k fp32 dead -> no race)
  if (!bigws)
    prep_v<<<B_ * NC_, 256, 0, stream>>>(v, vbH, vbL);
  // 4) FUSED per-chunk kv outer products + exclusive scan (fp32 prefix in
  //    registers) -> split frag-tiled bf16 kvb.
  chunk_kvscan_kernel<<<16 * 16, 256, 0, stream>>>(kf, v, kvbH, kvbL);
  // 5) MFMA inter+intra chunk attention -> A-tiled split bf16 (fused epilogue)
  chunk_attn_kernel<<<B_ * H_ * NC_, 256, 0, stream>>>(qf, kf, vbH, vbL,
                                                       kvbH, kvbL, oHt, oLt);
  // 6) Output projection (fallback path tiles Wo late)
  if (!bigws)
    wtrans_wo<<<dim3(16, 64), 256, 0, stream>>>(Wo, WoTh);
  mfma_wo<<<dim3(16, 32), 256, 0, stream>>>(oHt, oLt, WoTh, out);
}

// Round 13
// 480.553 us; speedup vs baseline: 1.0500x; 1.0500x over previous
//
#include <hip/hip_runtime.h>

#define B_ 2
#define L_ 2048
#define D_ 2048
#define H_ 8
#define HD_ 256
#define FD_ 64
#define F_ 128          // 2*FD
#define NC_ 32          // L/CHUNK
#define M_ (B_*L_)      // 4096
#define SCALE_Q 0.08838834764831845f   // 128^-0.5

typedef unsigned short u16;
typedef __attribute__((ext_vector_type(8))) short bf16x8;
typedef __attribute__((ext_vector_type(8))) unsigned short u16x8;
typedef __attribute__((ext_vector_type(4))) unsigned short u16x4;
typedef __attribute__((ext_vector_type(16))) float f32x16;
typedef __attribute__((ext_vector_type(4))) unsigned int u32x4;

#define FMA4(a_, s_, v_) { (a_).x += (s_)*(v_).x; (a_).y += (s_)*(v_).y; \
                           (a_).z += (s_)*(v_).z; (a_).w += (s_)*(v_).w; }

// ---------------------------------------------------------------------------
// Tiled operand layouts (read-major: memory order == MFMA fragment order).
// 512-u16 chunk (one 32xK16 fragment set): addr = ((k>>3)&1)*256 + (x&31)*8
// + (k&7). Lane l reads u16x8 at chunk + l*8 -> (x = l&31, k = ks*16 +
// (l>>5)*8 + elem). Symmetric between A-frags and B-frags.
// ---------------------------------------------------------------------------

__device__ __forceinline__ u16 bf16_rne(float x) {
  unsigned u = __float_as_uint(x);
  return (u16)((u + 0x7fffu + ((u >> 16) & 1u)) >> 16);
}
__device__ __forceinline__ void bf16_split(float x, u16& h, u16& l) {
  unsigned u = __float_as_uint(x);
  unsigned hb = (u + 0x7fffu + ((u >> 16) & 1u)) >> 16;
  h = (u16)hb;
  float hf = __uint_as_float(hb << 16);
  l = bf16_rne(x - hf);
}

__device__ __forceinline__ void gl_lds16(const u16* g, u16* l) {
  __builtin_amdgcn_global_load_lds(
      (const __attribute__((address_space(1))) unsigned int*)g,
      (__attribute__((address_space(3))) unsigned int*)l, 16, 0, 0);
}

// kvb frag-tiled offset: per-chunk [2 d-panel][4 f-kt][4096] (F=128,HD=256).
__device__ __forceinline__ size_t kvb_off(int d, int f) {
  return (size_t)(((d >> 7) & 1) * 16384 + ((f >> 5) & 3) * 4096 +
                  ((d >> 6) & 1) * 2048 + ((f >> 4) & 1) * 1024 +
                  ((d >> 5) & 1) * 512 + ((f >> 3) & 1) * 256 +
                  (d & 31) * 8 + (f & 7));
}
// vb frag-tiled offset: per-chunk (J=64,HD=256) -> 16384 u16.
__device__ __forceinline__ size_t vb_off(int d, int j) {
  return (size_t)(((d >> 7) & 1) * 8192 + ((j >> 5) & 1) * 4096 +
                  ((d >> 6) & 1) * 2048 + ((j >> 4) & 1) * 1024 +
                  ((d >> 5) & 1) * 512 + ((j >> 3) & 1) * 256 +
                  (d & 31) * 8 + (j & 7));
}

// ---------------------------------------------------------------------------
// W[K=2048][Nsrc] fp32 -> B-tiled bf16 (panel P, ktile kt).
// ---------------------------------------------------------------------------
__device__ __forceinline__ void wtrans_body(const float* __restrict__ W, int Nsrc,
                                            int n0, u16* __restrict__ dst,
                                            int P, int kt) {
  int t = threadIdx.x;
  int nn = t & 127, kh = t >> 7;
  const float* src = W + (size_t)(kt * 32 + kh * 16) * Nsrc + n0 + nn;
  u16x8 u0, u1;
  #pragma unroll
  for (int kk = 0; kk < 8; ++kk) u0[kk] = bf16_rne(src[(size_t)kk * Nsrc]);
  #pragma unroll
  for (int kk = 0; kk < 8; ++kk) u1[kk] = bf16_rne(src[(size_t)(kk + 8) * Nsrc]);
  size_t base = ((size_t)P * 64 + kt) * 4096 + (size_t)((nn >> 6) & 1) * 2048
              + (size_t)kh * 1024 + (size_t)((nn >> 5) & 1) * 512
              + (size_t)(nn & 31) * 8;
  *(u16x8*)(dst + base) = u0;
  *(u16x8*)(dst + base + 256) = u1;
}

// Fused prep: hs split (0..4095) + Wq|Wk|Wv tiling (4096..5375) +
// fmq/fmk B-frag tiling (5376..5503) + (bigws) Wo tiling (5504..6527).
__global__ __launch_bounds__(256)
void prep_kernel(const float* __restrict__ hs,
                 const float* __restrict__ Wq, const float* __restrict__ Wk,
                 const float* __restrict__ Wv, const float* __restrict__ Wo,
                 const float* __restrict__ fmq, const float* __restrict__ fmk,
                 u16* __restrict__ hsHt, u16* __restrict__ hsLt,
                 u16* __restrict__ WTh, u16* __restrict__ WoTh,
                 u16* __restrict__ fmbtH, u16* __restrict__ fmbtL) {
  int bid = blockIdx.x;
  if (bid < 4096) {
    int gid = bid * 256 + threadIdx.x;
    int r = gid >> 8, u = gid & 255;
    const float* src = hs + (size_t)r * 2048 + u * 8;
    float4 v0 = *(const float4*)src, v1 = *(const float4*)(src + 4);
    float vals[8] = {v0.x, v0.y, v0.z, v0.w, v1.x, v1.y, v1.z, v1.w};
    u16x8 hv, lv;
    #pragma unroll
    for (int j = 0; j < 8; ++j) { u16 hh, ll; bf16_split(vals[j], hh, ll); hv[j] = hh; lv[j] = ll; }
    size_t off = ((size_t)(r >> 6) * 64 + (u >> 2)) * 2048
               + (size_t)((u >> 1) & 1) * 1024 + (size_t)((r >> 5) & 1) * 512
               + (size_t)(u & 1) * 256 + (size_t)(r & 31) * 8;
    *(u16x8*)(hsHt + off) = hv;
    *(u16x8*)(hsLt + off) = lv;
  } else if (bid < 5376) {
    int idx = bid - 4096;
    int P = idx >> 6, kt = idx & 63;
    const float* W; int Nsrc, n0;
    if (P < 16)      { W = Wq; Nsrc = 2048; n0 = P * 128; }
    else if (P < 18) { W = Wk; Nsrc = 256;  n0 = (P - 16) * 128; }
    else             { W = Wv; Nsrc = 256;  n0 = (P - 18) * 128; }
    wtrans_body(W, Nsrc, n0, WTh, P, kt);
  } else if (bid < 5504) {
    // fm B-frag tiling: per (h16, kt): 64 cols x 32 k -> 2048-u16 chunk.
    int idx = bid - 5376;                  // 0..127
    int h16 = idx >> 3, kt = idx & 7;
    const float* src = (h16 < 8) ? (fmq + (size_t)h16 * 16384)
                                 : (fmk + (size_t)(h16 - 8) * 16384);
    int t = threadIdx.x;
    int f = t & 63, kq = t >> 6;           // k = kq*8 + i
    u16x8 hv, lv;
    #pragma unroll
    for (int i = 0; i < 8; ++i) {
      float val = src[(size_t)(kt * 32 + kq * 8 + i) * 64 + f];
      u16 hh, ll; bf16_split(val, hh, ll); hv[i] = hh; lv[i] = ll;
    }
    size_t base = (size_t)(h16 * 8 + kt) * 2048 + (size_t)(kq >> 1) * 1024
                + (size_t)(f >> 5) * 512 + (size_t)(kq & 1) * 256
                + (size_t)(f & 31) * 8;
    *(u16x8*)(fmbtH + base) = hv;
    *(u16x8*)(fmbtL + base) = lv;
  } else {
    int idx = bid - 5504;
    wtrans_body(Wo, 2048, (idx >> 6) * 128, WoTh, idx >> 6, idx & 63);
  }
}

// Fallback standalone Wo tiling (small-workspace path).
__global__ __launch_bounds__(256)
void wtrans_wo(const float* __restrict__ Wo, u16* __restrict__ WoTh) {
  wtrans_body(Wo, 2048, blockIdx.x * 128, WoTh, blockIdx.x, blockIdx.y);
}

// Standalone prep_v (fallback path; bigws fuses into mfma_hh).
__global__ __launch_bounds__(256)
void prep_v(const float* __restrict__ v, u16* __restrict__ vbH,
            u16* __restrict__ vbL) {
  int bn = blockIdx.x;
  const float* vp = v + (size_t)bn * 64 * HD_;
  size_t cbout = (size_t)bn * 16384;
  int d = threadIdx.x;
  #pragma unroll
  for (int it = 0; it < 8; ++it) {
    int j0 = it * 8;
    u16x8 hv, lv;
    #pragma unroll
    for (int c = 0; c < 8; ++c) {
      u16 hh, ll; bf16_split(vp[(size_t)(j0 + c) * HD_ + d], hh, ll);
      hv[c] = hh; lv[c] = ll;
    }
    size_t off = cbout + vb_off(d, j0);
    *(u16x8*)(vbH + off) = hv;
    *(u16x8*)(vbL + off) = lv;
  }
}

// ---------------------------------------------------------------------------
// OLD 2-pass split-bf16 MFMA GEMM (64x128 tile, BK=32, 128 threads).
// Kept for the small k/v projection (full 256-block grid; R6-verified).
// ---------------------------------------------------------------------------
__device__ __forceinline__ void mfma_body(
    const u16* __restrict__ AtH, const u16* __restrict__ AtL,
    const u16* __restrict__ Bt, float* __restrict__ C, int cstride,
    int bm, int bn) {
  __shared__ __align__(16) u16 AsH[2048];
  __shared__ __align__(16) u16 AsL[2048];
  __shared__ __align__(16) u16 Bs[4096];
  const int t = threadIdx.x, lane = t & 63, wv = t >> 6;
  const u16* aSrc = (wv ? AtL : AtH) + (size_t)bm * 131072 + lane * 8;
  const u16* bSrc = Bt + (size_t)bn * 262144 + wv * 2048 + lane * 8;
  u16* aDst = wv ? AsL : AsH;
  u16* bDst = Bs + wv * 2048;

  f32x16 acc[2][2];
  #pragma unroll
  for (int a = 0; a < 2; ++a)
    #pragma unroll
    for (int b2 = 0; b2 < 2; ++b2)
      #pragma unroll
      for (int r = 0; r < 16; ++r) acc[a][b2][r] = 0.f;

  for (int kt = 0; kt < 64; ++kt) {
    const u16* ak = aSrc + (size_t)kt * 2048;
    const u16* bk = bSrc + (size_t)kt * 4096;
    __syncthreads();
    #pragma unroll
    for (int c = 0; c < 4; ++c) {
      gl_lds16(ak + c * 512, aDst + c * 512);
      gl_lds16(bk + c * 512, bDst + c * 512);
    }
    __syncthreads();

    #pragma unroll
    for (int ks = 0; ks < 2; ++ks) {
      const u16* ph = AsH + ks * 1024 + lane * 8;
      const u16* pl = AsL + ks * 1024 + lane * 8;
      const u16* pb = Bs + wv * 2048 + ks * 1024 + lane * 8;
      bf16x8 a0 = *(const bf16x8*)ph;
      bf16x8 a1 = *(const bf16x8*)(ph + 512);
      bf16x8 b0 = *(const bf16x8*)pb;
      bf16x8 b1 = *(const bf16x8*)(pb + 512);
      acc[0][0] = __builtin_amdgcn_mfma_f32_32x32x16_bf16(a0, b0, acc[0][0], 0, 0, 0);
      acc[0][1] = __builtin_amdgcn_mfma_f32_32x32x16_bf16(a0, b1, acc[0][1], 0, 0, 0);
      acc[1][0] = __builtin_amdgcn_mfma_f32_32x32x16_bf16(a1, b0, acc[1][0], 0, 0, 0);
      acc[1][1] = __builtin_amdgcn_mfma_f32_32x32x16_bf16(a1, b1, acc[1][1], 0, 0, 0);
      bf16x8 l0 = *(const bf16x8*)pl;
      bf16x8 l1 = *(const bf16x8*)(pl + 512);
      acc[0][0] = __builtin_amdgcn_mfma_f32_32x32x16_bf16(l0, b0, acc[0][0], 0, 0, 0);
      acc[0][1] = __builtin_amdgcn_mfma_f32_32x32x16_bf16(l0, b1, acc[0][1], 0, 0, 0);
      acc[1][0] = __builtin_amdgcn_mfma_f32_32x32x16_bf16(l1, b0, acc[1][0], 0, 0, 0);
      acc[1][1] = __builtin_amdgcn_mfma_f32_32x32x16_bf16(l1, b1, acc[1][1], 0, 0, 0);
    }
  }

  const int fr = lane & 31, g = lane >> 5;
  float* Cp = C + (size_t)(bm * 64) * cstride + wv * 64;
  #pragma unroll
  for (int mt = 0; mt < 2; ++mt)
    #pragma unroll
    for (int nt = 0; nt < 2; ++nt) {
      #pragma unroll
      for (int r = 0; r < 16; ++r) {
        int row = mt * 32 + (r & 3) + 8 * (r >> 2) + 4 * g;
        Cp[(size_t)row * cstride + nt * 32 + fr] = acc[mt][nt][r];
      }
    }
}

// ---------------------------------------------------------------------------
// Pipelined body v3: 128x128 tile, 4 waves, BK=32, triple ring (72 KB ->
// 2 blocks/CU), phase-split + counted vmcnt(6) + setprio. (R9: 68us, 44%.)
// ---------------------------------------------------------------------------
#define SUB_ 12288
#define MFB(a_, b_, c_) (c_) = __builtin_amdgcn_mfma_f32_32x32x16_bf16((a_), (b_), (c_), 0, 0, 0)

__device__ __forceinline__ void mfma_big_body(
    const u16* __restrict__ AtH, const u16* __restrict__ AtL,
    const u16* __restrict__ Bt, float* __restrict__ C, int cstride,
    int bm, int bn) {
  __shared__ __align__(16) u16 lds[3 * SUB_];
  const int t = threadIdx.x, lane = t & 63, wv = t >> 6;
  const int wm = wv >> 1, wn = wv & 1;

  const u16* gs[6];
  unsigned lo[6], gst[6];
  #pragma unroll
  for (int j = 0; j < 6; ++j) {
    int line = wv * 6 + j;
    if (line < 8) {
      gs[j] = AtH + ((size_t)(2 * bm + (line >> 2)) * 64) * 2048
                  + (size_t)(line & 3) * 512 + lane * 8;
      gst[j] = 2048;
    } else if (line < 16) {
      int l2 = line - 8;
      gs[j] = AtL + ((size_t)(2 * bm + (l2 >> 2)) * 64) * 2048
                  + (size_t)(l2 & 3) * 512 + lane * 8;
      gst[j] = 2048;
    } else {
      int l3 = line - 16;
      gs[j] = Bt + (size_t)bn * 262144 + (size_t)l3 * 512 + lane * 8;
      gst[j] = 4096;
    }
    lo[j] = line * 512;
  }

  f32x16 acc[2][2];
  #pragma unroll
  for (int a = 0; a < 2; ++a)
    #pragma unroll
    for (int b2 = 0; b2 < 2; ++b2)
      #pragma unroll
      for (int r = 0; r < 16; ++r) acc[a][b2][r] = 0.f;

  #pragma unroll
  for (int j = 0; j < 6; ++j) gl_lds16(gs[j], lds + lo[j]);
  #pragma unroll
  for (int j = 0; j < 6; ++j) gl_lds16(gs[j] + gst[j], lds + SUB_ + lo[j]);
  asm volatile("s_waitcnt vmcnt(6)" ::: "memory");
  __builtin_amdgcn_s_barrier();
  __builtin_amdgcn_sched_barrier(0);

  int cb = 0;
  for (int kt = 0; kt < 64; ++kt) {
    int sb = cb + 2 * SUB_; if (sb >= 3 * SUB_) sb -= 3 * SUB_;
    const u16* base = lds + cb;
    const u16* ph0 = base + wm * 2048 + lane * 8;
    const u16* pb0 = base + 8192 + wn * 2048 + lane * 8;

    bf16x8 a0 = *(const bf16x8*)(ph0);
    bf16x8 a1 = *(const bf16x8*)(ph0 + 512);
    bf16x8 l0 = *(const bf16x8*)(ph0 + 4096);
    bf16x8 l1 = *(const bf16x8*)(ph0 + 4608);
    bf16x8 b0 = *(const bf16x8*)(pb0);
    bf16x8 b1 = *(const bf16x8*)(pb0 + 512);
    if (kt < 62) {
      gl_lds16(gs[0] + (size_t)(kt + 2) * gst[0], lds + sb + lo[0]);
      gl_lds16(gs[1] + (size_t)(kt + 2) * gst[1], lds + sb + lo[1]);
      gl_lds16(gs[2] + (size_t)(kt + 2) * gst[2], lds + sb + lo[2]);
    }
    __builtin_amdgcn_s_barrier();
    asm volatile("s_waitcnt lgkmcnt(0)" ::: "memory");
    __builtin_amdgcn_sched_barrier(0);
    __builtin_amdgcn_s_setprio(1);
    MFB(a0, b0, acc[0][0]); MFB(a0, b1, acc[0][1]);
    MFB(a1, b0, acc[1][0]); MFB(a1, b1, acc[1][1]);
    MFB(l0, b0, acc[0][0]); MFB(l0, b1, acc[0][1]);
    MFB(l1, b0, acc[1][0]); MFB(l1, b1, acc[1][1]);
    __builtin_amdgcn_s_setprio(0);
    __builtin_amdgcn_s_barrier();
    __builtin_amdgcn_sched_barrier(0);

    bf16x8 c0 = *(const bf16x8*)(ph0 + 1024);
    bf16x8 c1 = *(const bf16x8*)(ph0 + 1536);
    bf16x8 m0 = *(const bf16x8*)(ph0 + 5120);
    bf16x8 m1 = *(const bf16x8*)(ph0 + 5632);
    bf16x8 d0 = *(const bf16x8*)(pb0 + 1024);
    bf16x8 d1 = *(const bf16x8*)(pb0 + 1536);
    if (kt < 62) {
      gl_lds16(gs[3] + (size_t)(kt + 2) * gst[3], lds + sb + lo[3]);
      gl_lds16(gs[4] + (size_t)(kt + 2) * gst[4], lds + sb + lo[4]);
      gl_lds16(gs[5] + (size_t)(kt + 2) * gst[5], lds + sb + lo[5]);
    }
    __builtin_amdgcn_s_barrier();
    asm volatile("s_waitcnt lgkmcnt(0)" ::: "memory");
    __builtin_amdgcn_sched_barrier(0);
    __builtin_amdgcn_s_setprio(1);
    MFB(c0, d0, acc[0][0]); MFB(c0, d1, acc[0][1]);
    MFB(c1, d0, acc[1][0]); MFB(c1, d1, acc[1][1]);
    MFB(m0, d0, acc[0][0]); MFB(m0, d1, acc[0][1]);
    MFB(m1, d0, acc[1][0]); MFB(m1, d1, acc[1][1]);
    __builtin_amdgcn_s_setprio(0);
    if (kt < 62) asm volatile("s_waitcnt vmcnt(6)" ::: "memory");
    else         asm volatile("s_waitcnt vmcnt(0)" ::: "memory");
    __builtin_amdgcn_s_barrier();
    __builtin_amdgcn_sched_barrier(0);
    cb += SUB_; if (cb == 3 * SUB_) cb = 0;
  }

  const int fr = lane & 31, g = lane >> 5;
  float* Cp = C + (size_t)(bm * 128 + wm * 64) * cstride + wn * 64;
  #pragma unroll
  for (int mt = 0; mt < 2; ++mt)
    #pragma unroll
    for (int nt = 0; nt < 2; ++nt) {
      #pragma unroll
      for (int r = 0; r < 16; ++r) {
        int row = mt * 32 + (r & 3) + 8 * (r >> 2) + 4 * g;
        Cp[(size_t)row * cstride + nt * 32 + fr] = acc[mt][nt][r];
      }
    }
}

// q projection: grid (16,32) = 512 blocks = exactly 2/CU (R9-verified).
__global__ __launch_bounds__(256, 2)
void mfma_q(const u16* __restrict__ hsHt, const u16* __restrict__ hsLt,
            const u16* __restrict__ WTh, float* __restrict__ q) {
  mfma_big_body(hsHt, hsLt, WTh, q + blockIdx.x * 128, 2048,
                blockIdx.y, blockIdx.x);
}

// k/v projections: old body, grid (4,64) = 256 blocks (R6-verified).
__global__ __launch_bounds__(128, 4)
void mfma_kv(const u16* __restrict__ hsHt, const u16* __restrict__ hsLt,
             const u16* __restrict__ WTh,
             float* __restrict__ k, float* __restrict__ v) {
  int bn = blockIdx.x;
  float* Cb; int co;
  if (bn < 2) { Cb = k; co = bn * 128; }
  else        { Cb = v; co = (bn - 2) * 128; }
  mfma_body(hsHt, hsLt, WTh, Cb + co, 256, blockIdx.y, 16 + bn);
}

__global__ __launch_bounds__(256, 2)
void mfma_wo(const u16* __restrict__ oHt, const u16* __restrict__ oLt,
             const u16* __restrict__ WoTh, float* __restrict__ out) {
  mfma_big_body(oHt, oLt, WoTh, out + blockIdx.x * 128, 2048,
                blockIdx.y, blockIdx.x);
}

// ---------------------------------------------------------------------------
// mfma_hh: RoPE + hedgehog projection via MFMA. (R9-verified.)
// ---------------------------------------------------------------------------
__global__ __launch_bounds__(256, 1)
void mfma_hh(const float* __restrict__ q, const float* __restrict__ kx,
             const float* __restrict__ cosb, const float* __restrict__ sinb,
             const u16* __restrict__ fmbtH, const u16* __restrict__ fmbtL,
             float* __restrict__ qf, float* __restrict__ kf,
             const float* __restrict__ vsrc,
             u16* __restrict__ vbH, u16* __restrict__ vbL) {
  int bid = blockIdx.x;
  if (bid >= 512) {                     // fused prep_v (bigws path)
    int bn = bid - 512;
    const float* vp = vsrc + (size_t)bn * 64 * HD_;
    size_t cbout = (size_t)bn * 16384;
    int d = threadIdx.x;
    #pragma unroll
    for (int it = 0; it < 8; ++it) {
      int j0 = it * 8;
      u16x8 hv, lv;
      #pragma unroll
      for (int c = 0; c < 8; ++c) {
        u16 hh, ll; bf16_split(vp[(size_t)(j0 + c) * HD_ + d], hh, ll);
        hv[c] = hh; lv[c] = ll;
      }
      size_t off = cbout + vb_off(d, j0);
      *(u16x8*)(vbH + off) = hv;
      *(u16x8*)(vbL + off) = lv;
    }
    return;
  }
  __shared__ __align__(16) u16 xlds[65536];   // [kt][rt32][hl][1024]
  const int t = threadIdx.x;
  const int rt = bid & 31, h16 = bid >> 5;
  const int rowbase = rt * 128;
  const float* xsrc; size_t xstr;
  if (h16 < 8) { xsrc = q + (size_t)h16 * 256; xstr = 2048; }
  else         { xsrc = kx;                    xstr = 256; }

  // ---- stage: RoPE + split -> A-frag LDS ----
  for (int iter = 0; iter < 16; ++iter) {
    int flat = iter * 1024 + t * 4;          // 128 rows x 128 dd
    int r = flat >> 7, dd = flat & 127;
    int grow = rowbase + r;
    int l = grow & 2047;
    const float* xr = xsrc + (size_t)grow * xstr + dd;
    float4 x1 = *(const float4*)xr;
    float4 x2 = *(const float4*)(xr + 128);
    float4 c  = *(const float4*)(cosb + (size_t)l * 128 + dd);
    float4 s  = *(const float4*)(sinb + (size_t)l * 128 + dd);
    float lo4[4] = {x1.x*c.x - x2.x*s.x, x1.y*c.y - x2.y*s.y,
                    x1.z*c.z - x2.z*s.z, x1.w*c.w - x2.w*s.w};
    float hi4[4] = {x1.x*s.x + x2.x*c.x, x1.y*s.y + x2.y*c.y,
                    x1.z*s.z + x2.z*c.z, x1.w*s.w + x2.w*c.w};
    int rt32 = r >> 5, r5 = r & 31;
    #pragma unroll
    for (int half = 0; half < 2; ++half) {
      int d = dd + half * 128;
      int kt = d >> 5, k = d & 31;
      unsigned base = (unsigned)((kt * 4 + rt32) * 2) * 1024
                    + (unsigned)(k >> 4) * 512 + (unsigned)((k >> 3) & 1) * 256
                    + (unsigned)r5 * 8 + (unsigned)(k & 7);
      const float* vv = half ? hi4 : lo4;
      u16x4 hv, lv;
      #pragma unroll
      for (int j = 0; j < 4; ++j) {
        u16 hh, ll; bf16_split(vv[j], hh, ll); hv[j] = hh; lv[j] = ll;
      }
      *(u16x4*)(xlds + base) = hv;
      *(u16x4*)(xlds + 1024 + base) = lv;
    }
  }
  __syncthreads();

  // ---- MFMA: wave w = rowtile, both nt; 3-pass split ----
  const int w = t >> 6, lane = t & 63;
  f32x16 acc[2];
  #pragma unroll
  for (int nt = 0; nt < 2; ++nt)
    #pragma unroll
    for (int r = 0; r < 16; ++r) acc[nt][r] = 0.f;

  const u16* fmbH = fmbtH + (size_t)h16 * 8 * 2048;
  const u16* fmbL = fmbtL + (size_t)h16 * 8 * 2048;
  #pragma unroll
  for (int kt = 0; kt < 8; ++kt) {
    unsigned xb = (unsigned)((kt * 4 + w) * 2) * 1024;
    #pragma unroll
    for (int ks = 0; ks < 2; ++ks) {
      bf16x8 xh = *(const bf16x8*)(xlds + xb + ks * 512 + lane * 8);
      bf16x8 xl = *(const bf16x8*)(xlds + xb + 1024 + ks * 512 + lane * 8);
      #pragma unroll
      for (int nt = 0; nt < 2; ++nt) {
        size_t fb = (size_t)kt * 2048 + ks * 1024 + nt * 512 + lane * 8;
        bf16x8 bh_ = *(const bf16x8*)((const short*)(fmbH + fb));
        bf16x8 bl_ = *(const bf16x8*)((const short*)(fmbL + fb));
        MFB(xh, bh_, acc[nt]); MFB(xl, bh_, acc[nt]); MFB(xh, bl_, acc[nt]);
      }
    }
  }

  // ---- softmax over concat(p,-p) + store qf/kf ----
  const int g = lane >> 5, f31 = lane & 31;
  float* outp = (h16 < 8) ? qf : kf;
  const int hh = h16 & 7;
  #pragma unroll
  for (int r = 0; r < 16; ++r) {
    int rowl = (r & 3) + 8 * (r >> 2) + 4 * g;
    int grow = rowbase + w * 32 + rowl;
    float p0 = acc[0][r], p1 = acc[1][r];
    float m = fmaxf(fabsf(p0), fabsf(p1));
    #pragma unroll
    for (int off = 16; off > 0; off >>= 1) m = fmaxf(m, __shfl_xor(m, off, 64));
    float e0 = __expf(p0 - m),  e0n = __expf(-p0 - m);
    float e1 = __expf(p1 - m),  e1n = __expf(-p1 - m);
    float zl = e0 + e0n + e1 + e1n;
    #pragma unroll
    for (int off = 16; off > 0; off >>= 1) zl += __shfl_xor(zl, off, 64);
    float inv = 1.0f / zl;
    int b = grow >> 11, l = grow & 2047;
    size_t ob = ((size_t)((b * 8 + hh) * 2048 + l)) * 128;
    outp[ob + f31]       = e0 * inv;
    outp[ob + 32 + f31]  = e1 * inv;
    outp[ob + 64 + f31]  = e0n * inv;
    outp[ob + 96 + f31]  = e1n * inv;
  }
}

// ---------------------------------------------------------------------------
// Phase A: per-chunk kv_n[f][d] outer products -> frag-tiled split bf16.
// (R9-verified pair restored; kvscan fusion reverted per R10 falsifier.)
// ---------------------------------------------------------------------------
__global__ __launch_bounds__(256)
void chunk_kv_kernel(const float* __restrict__ kf, const float* __restrict__ v,
                     u16* __restrict__ kvbH, u16* __restrict__ kvbL) {
  __shared__ __align__(16) float kfs[64][128];
  int n = blockIdx.x & (NC_ - 1), bh = blockIdx.x >> 5;
  int b = bh >> 3;
  const float* kfp = kf + ((size_t)bh * L_ + (size_t)n * 64) * F_;
  int t = threadIdx.x;
  #pragma unroll
  for (int it = 0; it < 8; ++it) {
    int flat = t * 4 + it * 1024;
    *(float4*)&kfs[flat >> 7][flat & 127] = *(const float4*)(kfp + flat);
  }
  __syncthreads();
  int dg = t & 63;
  int fg = t >> 6;
  const float* vp = v + (size_t)(b * L_ + n * 64) * HD_ + dg * 4;
  size_t cb = (size_t)blockIdx.x * 32768;
  #pragma unroll
  for (int pass = 0; pass < 4; ++pass) {
    int f0 = fg * 8 + pass * 32;
    float4 acc[8];
    #pragma unroll
    for (int i = 0; i < 8; ++i) acc[i] = make_float4(0.f, 0.f, 0.f, 0.f);
    for (int j = 0; j < 64; ++j) {
      float4 vv = *(const float4*)(vp + (size_t)j * HD_);
      float4 ka = *(const float4*)&kfs[j][f0];
      float4 kb = *(const float4*)&kfs[j][f0 + 4];
      FMA4(acc[0], ka.x, vv); FMA4(acc[1], ka.y, vv);
      FMA4(acc[2], ka.z, vv); FMA4(acc[3], ka.w, vv);
      FMA4(acc[4], kb.x, vv); FMA4(acc[5], kb.y, vv);
      FMA4(acc[6], kb.z, vv); FMA4(acc[7], kb.w, vv);
    }
    #pragma unroll
    for (int c = 0; c < 4; ++c) {
      u16x8 hv, lv;
      #pragma unroll
      for (int ff = 0; ff < 8; ++ff) {
        float xs = (c == 0) ? acc[ff].x : (c == 1) ? acc[ff].y
                 : (c == 2) ? acc[ff].z : acc[ff].w;
        u16 hh, ll; bf16_split(xs, hh, ll); hv[ff] = hh; lv[ff] = ll;
      }
      int d = dg * 4 + c;
      size_t off = cb + kvb_off(d, f0);
      *(u16x8*)(kvbH + off) = hv;
      *(u16x8*)(kvbL + off) = lv;
    }
  }
}

// Phase B: in-place exclusive prefix over the 32 chunks, on split bf16.
__global__ __launch_bounds__(256)
void chunk_scan_kernel(u16* __restrict__ kvbH, u16* __restrict__ kvbL) {
  int bh = blockIdx.x >> 4, g = blockIdx.x & 15;
  int d = threadIdx.x;
  size_t off = kvb_off(d, g * 8);
  float run[8] = {0.f, 0.f, 0.f, 0.f, 0.f, 0.f, 0.f, 0.f};
  for (int n = 0; n < NC_; ++n) {
    size_t a = ((size_t)(bh * 32 + n)) * 32768 + off;
    u16x8 hv = *(u16x8*)(kvbH + a);
    u16x8 lv = *(u16x8*)(kvbL + a);
    u16x8 oh, ol;
    #pragma unroll
    for (int c = 0; c < 8; ++c) {
      float val = __uint_as_float((unsigned)hv[c] << 16)
                + __uint_as_float((unsigned)lv[c] << 16);
      u16 hh, ll; bf16_split(run[c], hh, ll); oh[c] = hh; ol[c] = ll;
      run[c] += val;
    }
    *(u16x8*)(kvbH + a) = oh;
    *(u16x8*)(kvbL + a) = ol;
  }
}

// ---------------------------------------------------------------------------
// Phase C (MFMA): epilogue writes A-tiled split bf16 oHt/oLt directly.
// ---------------------------------------------------------------------------
__global__ __launch_bounds__(256, 2)
void chunk_attn_kernel(const float* __restrict__ qf, const float* __restrict__ kf,
                       const u16* __restrict__ vbH, const u16* __restrict__ vbL,
                       const u16* __restrict__ kvbH, const u16* __restrict__ kvbL,
                       u16* __restrict__ oHt, u16* __restrict__ oLt) {
  __shared__ __align__(16) u16 lds[32768];   // qsH|qsL|kfH|kfL
  const int n = blockIdx.x & (NC_ - 1), bh = blockIdx.x >> 5;
  const int h = bh & 7, b = bh >> 3;
  const int t = threadIdx.x;
  const int w = t >> 6, i31 = t & 31, G = (t >> 5) & 1;
  const int l8 = (t & 63) * 8;

  {
    const float* qp = qf + ((size_t)bh * L_ + (size_t)n * 64) * F_;
    const float* kp = kf + ((size_t)bh * L_ + (size_t)n * 64) * F_;
    int o8 = t & 15, ib = t >> 4;
    #pragma unroll
    for (int iter = 0; iter < 4; ++iter) {
      int i = ib + iter * 16;
      int it = i >> 5, ks = o8 >> 1;
      int sub = (it * 8 + ks) * 512 + (o8 & 1) * 256 + (i & 31) * 8;
      {
        const float* src = qp + (size_t)i * 128 + o8 * 8;
        float4 a = *(const float4*)src, c = *(const float4*)(src + 4);
        float vals[8] = {a.x, a.y, a.z, a.w, c.x, c.y, c.z, c.w};
        u16x8 hv, lv;
        #pragma unroll
        for (int j = 0; j < 8; ++j) {
          u16 hh, ll; bf16_split(vals[j] * SCALE_Q, hh, ll);
          hv[j] = hh; lv[j] = ll;
        }
        *(u16x8*)(lds + sub) = hv;
        *(u16x8*)(lds + 8192 + sub) = lv;
      }
      {
        const float* src = kp + (size_t)i * 128 + o8 * 8;
        float4 a = *(const float4*)src, c = *(const float4*)(src + 4);
        float vals[8] = {a.x, a.y, a.z, a.w, c.x, c.y, c.z, c.w};
        u16x8 hv, lv;
        #pragma unroll
        for (int j = 0; j < 8; ++j) {
          u16 hh, ll; bf16_split(vals[j], hh, ll);
          hv[j] = hh; lv[j] = ll;
        }
        *(u16x8*)(lds + 16384 + sub) = hv;
        *(u16x8*)(lds + 24576 + sub) = lv;
      }
    }
  }
  __syncthreads();

  const u16* Lq  = lds;
  const u16* Lql = lds + 8192;
  const u16* Lk  = lds + 16384;
  const u16* Lkl = lds + 24576;

  // ---- phase S: sT = kf · qs^T (3-pass split) ----
  f32x16 st[2][2];
  #pragma unroll
  for (int a = 0; a < 2; ++a)
    #pragma unroll
    for (int c = 0; c < 2; ++c)
      #pragma unroll
      for (int r = 0; r < 16; ++r) st[a][c][r] = 0.f;

  #pragma unroll
  for (int ks = 0; ks < 8; ++ks) {
    bf16x8 kh0 = *(const bf16x8*)(Lk  + ks * 512 + l8);
    bf16x8 kh1 = *(const bf16x8*)(Lk  + (8 + ks) * 512 + l8);
    bf16x8 kl0 = *(const bf16x8*)(Lkl + ks * 512 + l8);
    bf16x8 kl1 = *(const bf16x8*)(Lkl + (8 + ks) * 512 + l8);
    bf16x8 qh0 = *(const bf16x8*)(Lq  + ks * 512 + l8);
    bf16x8 qh1 = *(const bf16x8*)(Lq  + (8 + ks) * 512 + l8);
    bf16x8 ql0 = *(const bf16x8*)(Lql + ks * 512 + l8);
    bf16x8 ql1 = *(const bf16x8*)(Lql + (8 + ks) * 512 + l8);
    MFB(kh0, qh0, st[0][0]); MFB(kh0, ql0, st[0][0]); MFB(kl0, qh0, st[0][0]);
    MFB(kh0, qh1, st[0][1]); MFB(kh0, ql1, st[0][1]); MFB(kl0, qh1, st[0][1]);
    MFB(kh1, qh0, st[1][0]); MFB(kh1, ql0, st[1][0]); MFB(kl1, qh0, st[1][0]);
    MFB(kh1, qh1, st[1][1]); MFB(kh1, ql1, st[1][1]); MFB(kl1, qh1, st[1][1]);
  }

  // ---- mask + split + cross-lane transpose: sT C-regs -> s A-frags ----
  bf16x8 sfH[2][4], sfL[2][4];
  #pragma unroll
  for (int mt = 0; mt < 2; ++mt) {
    int iv = mt * 32 + i31;
    #pragma unroll
    for (int ksj = 0; ksj < 4; ++ksj) {
      const int jt = ksj >> 1, kb = ksj & 1;
      unsigned ph[4], pl[4];
      #pragma unroll
      for (int half = 0; half < 2; ++half) {
        u16 hh[4], ll[4];
        #pragma unroll
        for (int c = 0; c < 4; ++c) {
          int r = 8 * kb + 4 * half + c;
          int jv = jt * 32 + (r & 3) + 8 * (r >> 2) + 4 * G;
          float mv = (jv <= iv) ? st[jt][mt][r] : 0.f;
          u16 h_, l_; bf16_split(mv, h_, l_);
          hh[c] = h_; ll[c] = l_;
        }
        ph[half * 2 + 0] = (unsigned)hh[0] | ((unsigned)hh[1] << 16);
        ph[half * 2 + 1] = (unsigned)hh[2] | ((unsigned)hh[3] << 16);
        pl[half * 2 + 0] = (unsigned)ll[0] | ((unsigned)ll[1] << 16);
        pl[half * 2 + 1] = (unsigned)ll[2] | ((unsigned)ll[3] << 16);
      }
      unsigned rH1 = (unsigned)__shfl_xor((int)(G ? ph[0] : ph[2]), 32, 64);
      unsigned rH2 = (unsigned)__shfl_xor((int)(G ? ph[1] : ph[3]), 32, 64);
      unsigned rL1 = (unsigned)__shfl_xor((int)(G ? pl[0] : pl[2]), 32, 64);
      unsigned rL2 = (unsigned)__shfl_xor((int)(G ? pl[1] : pl[3]), 32, 64);
      u32x4 wH, wL;
      wH[0] = G ? rH1 : ph[0]; wH[1] = G ? rH2 : ph[1];
      wH[2] = G ? ph[2] : rH1; wH[3] = G ? ph[3] : rH2;
      wL[0] = G ? rL1 : pl[0]; wL[1] = G ? rL2 : pl[1];
      wL[2] = G ? pl[2] : rL1; wL[3] = G ? pl[3] : rL2;
      sfH[mt][ksj] = __builtin_bit_cast(bf16x8, wH);
      sfL[mt][ksj] = __builtin_bit_cast(bf16x8, wL);
    }
  }

  f32x16 acc[2][2];
  #pragma unroll
  for (int a = 0; a < 2; ++a)
    #pragma unroll
    for (int c = 0; c < 2; ++c)
      #pragma unroll
      for (int r = 0; r < 16; ++r) acc[a][c][r] = 0.f;

  // ---- phase A (intra): acc += s · v, v frags pre-tiled ----
  {
    size_t vcb = ((size_t)(b * NC_ + n)) * 16384;
    #pragma unroll
    for (int nt = 0; nt < 2; ++nt) {
      #pragma unroll
      for (int ksj = 0; ksj < 4; ++ksj) {
        size_t basev = vcb + vb_off(w * 64 + nt * 32, ksj * 16) + l8;
        bf16x8 vH = *(const bf16x8*)((const short*)(vbH + basev));
        bf16x8 vL = *(const bf16x8*)((const short*)(vbL + basev));
        MFB(sfH[0][ksj], vH, acc[0][nt]); MFB(sfL[0][ksj], vH, acc[0][nt]);
        MFB(sfH[0][ksj], vL, acc[0][nt]);
        MFB(sfH[1][ksj], vH, acc[1][nt]); MFB(sfL[1][ksj], vH, acc[1][nt]);
        MFB(sfH[1][ksj], vL, acc[1][nt]);
      }
    }
  }

  // ---- phase I (inter): acc += qs · kv_cum ----
  {
    size_t cb = (size_t)blockIdx.x * 32768;
    #pragma unroll
    for (int ks = 0; ks < 8; ++ks) {
      bf16x8 qa_h0 = *(const bf16x8*)(Lq  + ks * 512 + l8);
      bf16x8 qa_h1 = *(const bf16x8*)(Lq  + (8 + ks) * 512 + l8);
      bf16x8 qa_l0 = *(const bf16x8*)(Lql + ks * 512 + l8);
      bf16x8 qa_l1 = *(const bf16x8*)(Lql + (8 + ks) * 512 + l8);
      #pragma unroll
      for (int nt = 0; nt < 2; ++nt) {
        size_t base = cb + kvb_off(w * 64 + nt * 32, ks * 16) + l8;
        bf16x8 kvH = *(const bf16x8*)((const short*)(kvbH + base));
        bf16x8 kvL = *(const bf16x8*)((const short*)(kvbL + base));
        MFB(qa_h0, kvH, acc[0][nt]); MFB(qa_l0, kvH, acc[0][nt]);
        MFB(qa_h0, kvL, acc[0][nt]);
        MFB(qa_h1, kvH, acc[1][nt]); MFB(qa_l1, kvH, acc[1][nt]);
        MFB(qa_h1, kvL, acc[1][nt]);
      }
    }
  }

  // ---- fused epilogue: A-tiled split bf16 write ----
  {
    int p = b * NC_ + n;
    #pragma unroll
    for (int mt = 0; mt < 2; ++mt)
      #pragma unroll
      for (int nt = 0; nt < 2; ++nt) {
        int u_ = h * 32 + w * 8 + nt * 4 + (i31 >> 3);
        size_t ob = ((size_t)p * 64 + (u_ >> 2)) * 2048
                  + (size_t)((u_ >> 1) & 1) * 1024 + (size_t)mt * 512
                  + (size_t)(u_ & 1) * 256 + (size_t)(i31 & 7);
        #pragma unroll
        for (int r = 0; r < 16; ++r) {
          int rr = (r & 3) + 8 * (r >> 2) + 4 * G;
          u16 hh, ll; bf16_split(acc[mt][nt][r], hh, ll);
          oHt[ob + (size_t)rr * 8] = hh;
          oLt[ob + (size_t)rr * 8] = ll;
        }
      }
  }
}

// ---------------------------------------------------------------------------
extern "C" void kernel_launch(void* const* d_in, const int* in_sizes, int n_in,
                              void* d_out, int out_size, void* d_ws, size_t ws_size,
                              hipStream_t stream) {
  const float* hs   = (const float*)d_in[0];
  const float* fcos = (const float*)d_in[1];
  const float* fsin = (const float*)d_in[2];
  // d_in[3] = mask (all ones, unused)
  const float* Wq  = (const float*)d_in[4];
  const float* Wk  = (const float*)d_in[5];
  const float* Wv  = (const float*)d_in[6];
  const float* Wo  = (const float*)d_in[7];
  const float* fmq = (const float*)d_in[8];
  const float* fmk = (const float*)d_in[9];
  float* out = (float*)d_out;

  float* ws = (float*)d_ws;
  float* q  = ws;                                   // 32MB; later oHt/oLt
  float* k  = q  + (size_t)M_ * 2048;               // 4MB; (!bigws: vb tiles)
  float* v  = k  + (size_t)M_ * 256;                // 4MB
  float* qf = v  + (size_t)M_ * 256;                // 16MB
  float* kf = qf + (size_t)B_ * H_ * L_ * F_;       // 16MB
  float* kvr = kf + (size_t)B_ * H_ * L_ * F_;      // 64MB region

  u16* hsHt = (u16*)kvr;                      // 16 MB
  u16* hsLt = hsHt + (size_t)M_ * 2048;       // 16 MB
  u16* WTh  = hsLt + (size_t)M_ * 2048;       // 10 MB
  // fm B-frag tiles in the dead tail of kvr (live until mfma_hh; kvb
  // overwrites kvr only later, in chunk_kv).
  u16* fmbtH = WTh + (size_t)1280 * 4096;     // 0.5 MB
  u16* fmbtL = fmbtH + (size_t)131072 * 2;    // 0.5 MB
  u16* kvbH = (u16*)kvr;                      // 32 MB
  u16* kvbL = kvbH + (size_t)512 * 32768;     // 32 MB
  u16* oHt  = (u16*)q;                        // 16 MB (q dead after mfma_hh)
  u16* oLt  = oHt + (size_t)M_ * 2048;        // 16 MB

  // bigws extras past the 136 MB base: WoTh (8 MB) + vb tiles (4 MB).
  const size_t WS_BASE = (size_t)142606336;   // 136 MB
  bool bigws = ws_size >= WS_BASE + (size_t)12582912;
  u16* WoTh = bigws ? (u16*)((char*)d_ws + WS_BASE) : (u16*)kvr;
  u16* vbH  = bigws ? (u16*)((char*)d_ws + WS_BASE + 8388608) : (u16*)k;
  u16* vbL  = vbH + (size_t)64 * 16384;

  // 1) Fused prep: hs split + Wq/Wk/Wv tiling + fm tiling (+ Wo when bigws)
  prep_kernel<<<bigws ? 6528 : 5504, 256, 0, stream>>>(
      hs, Wq, Wk, Wv, Wo, fmq, fmk, hsHt, hsLt, WTh, WoTh, fmbtH, fmbtL);
  // 2a) q projection: pipelined body, grid (16,32) = 512 blocks = 2/CU exact
  mfma_q<<<dim3(16, 32), 256, 0, stream>>>(hsHt, hsLt, WTh, q);
  // 2b) k/v projections: old body, 256 blocks
  mfma_kv<<<dim3(4, 64), 128, 0, stream>>>(hsHt, hsLt, WTh, k, v);
  // 3) MFMA RoPE+hedgehog; bigws fuses prep_v
  mfma_hh<<<bigws ? 576 : 512, 256, 0, stream>>>(
      q, k, fcos, fsin, fmbtH, fmbtL, qf, kf, v, vbH, vbL);
  // 3b) fallback prep_v AFTER mfma_hh (k fp32 dead -> no race)
  if (!bigws)
    prep_v<<<B_ * NC_, 256, 0, stream>>>(v, vbH, vbL);
  // 4) Per-chunk kv outer products + in-place exclusive scan (R9-verified
  //    pair; latency-bound kvscan fusion reverted)
  chunk_kv_kernel<<<B_ * H_ * NC_, 256, 0, stream>>>(kf, v, kvbH, kvbL);
  chunk_scan_kernel<<<256, 256, 0, stream>>>(kvbH, kvbL);
  // 5) MFMA inter+intra chunk attention -> A-tiled split bf16 (fused epilogue)
  chunk_attn_kernel<<<B_ * H_ * NC_, 256, 0, stream>>>(qf, kf, vbH, vbL,
                                                       kvbH, kvbL, oHt, oLt);
  // 6) Output projection (fallback path tiles Wo late)
  if (!bigws)
    wtrans_wo<<<dim3(16, 64), 256, 0, stream>>>(Wo, WoTh);
  mfma_wo<<<dim3(16, 32), 256, 0, stream>>>(oHt, oLt, WoTh, out);
}

// Round 14
// 466.110 us; speedup vs baseline: 1.0826x; 1.0310x over previous
//
#include <hip/hip_runtime.h>

#define B_ 2
#define L_ 2048
#define D_ 2048
#define H_ 8
#define HD_ 256
#define FD_ 64
#define F_ 128          // 2*FD
#define NC_ 32          // L/CHUNK
#define M_ (B_*L_)      // 4096
#define SCALE_Q 0.08838834764831845f   // 128^-0.5

typedef unsigned short u16;
typedef __attribute__((ext_vector_type(8))) short bf16x8;
typedef __attribute__((ext_vector_type(8))) unsigned short u16x8;
typedef __attribute__((ext_vector_type(4))) unsigned short u16x4;
typedef __attribute__((ext_vector_type(16))) float f32x16;
typedef __attribute__((ext_vector_type(4))) unsigned int u32x4;

// ---------------------------------------------------------------------------
// Tiled operand layouts (read-major: memory order == MFMA fragment order).
// 512-u16 chunk (one 32xK16 fragment set): addr = ((k>>3)&1)*256 + (x&31)*8
// + (k&7). Lane l reads u16x8 at chunk + l*8 -> (x = l&31, k = ks*16 +
// (l>>5)*8 + elem). Symmetric between A-frags and B-frags.
// ---------------------------------------------------------------------------

__device__ __forceinline__ u16 bf16_rne(float x) {
  unsigned u = __float_as_uint(x);
  return (u16)((u + 0x7fffu + ((u >> 16) & 1u)) >> 16);
}
__device__ __forceinline__ void bf16_split(float x, u16& h, u16& l) {
  unsigned u = __float_as_uint(x);
  unsigned hb = (u + 0x7fffu + ((u >> 16) & 1u)) >> 16;
  h = (u16)hb;
  float hf = __uint_as_float(hb << 16);
  l = bf16_rne(x - hf);
}

__device__ __forceinline__ void gl_lds16(const u16* g, u16* l) {
  __builtin_amdgcn_global_load_lds(
      (const __attribute__((address_space(1))) unsigned int*)g,
      (__attribute__((address_space(3))) unsigned int*)l, 16, 0, 0);
}

// kvb frag-tiled offset: per-chunk [2 d-panel][4 f-kt][4096] (F=128,HD=256).
__device__ __forceinline__ size_t kvb_off(int d, int f) {
  return (size_t)(((d >> 7) & 1) * 16384 + ((f >> 5) & 3) * 4096 +
                  ((d >> 6) & 1) * 2048 + ((f >> 4) & 1) * 1024 +
                  ((d >> 5) & 1) * 512 + ((f >> 3) & 1) * 256 +
                  (d & 31) * 8 + (f & 7));
}
// vb frag-tiled offset: per-chunk (J=64,HD=256) -> 16384 u16.
__device__ __forceinline__ size_t vb_off(int d, int j) {
  return (size_t)(((d >> 7) & 1) * 8192 + ((j >> 5) & 1) * 4096 +
                  ((d >> 6) & 1) * 2048 + ((j >> 4) & 1) * 1024 +
                  ((d >> 5) & 1) * 512 + ((j >> 3) & 1) * 256 +
                  (d & 31) * 8 + (j & 7));
}

// ---------------------------------------------------------------------------
// W[K=2048][Nsrc] fp32 -> B-tiled bf16 (panel P, ktile kt).
// ---------------------------------------------------------------------------
__device__ __forceinline__ void wtrans_body(const float* __restrict__ W, int Nsrc,
                                            int n0, u16* __restrict__ dst,
                                            int P, int kt) {
  int t = threadIdx.x;
  int nn = t & 127, kh = t >> 7;
  const float* src = W + (size_t)(kt * 32 + kh * 16) * Nsrc + n0 + nn;
  u16x8 u0, u1;
  #pragma unroll
  for (int kk = 0; kk < 8; ++kk) u0[kk] = bf16_rne(src[(size_t)kk * Nsrc]);
  #pragma unroll
  for (int kk = 0; kk < 8; ++kk) u1[kk] = bf16_rne(src[(size_t)(kk + 8) * Nsrc]);
  size_t base = ((size_t)P * 64 + kt) * 4096 + (size_t)((nn >> 6) & 1) * 2048
              + (size_t)kh * 1024 + (size_t)((nn >> 5) & 1) * 512
              + (size_t)(nn & 31) * 8;
  *(u16x8*)(dst + base) = u0;
  *(u16x8*)(dst + base + 256) = u1;
}

// Fused prep: hs split (0..4095) + Wq|Wk|Wv tiling (4096..5375) +
// fmq/fmk B-frag tiling (5376..5503) + (bigws) Wo tiling (5504..6527).
__global__ __launch_bounds__(256)
void prep_kernel(const float* __restrict__ hs,
                 const float* __restrict__ Wq, const float* __restrict__ Wk,
                 const float* __restrict__ Wv, const float* __restrict__ Wo,
                 const float* __restrict__ fmq, const float* __restrict__ fmk,
                 u16* __restrict__ hsHt, u16* __restrict__ hsLt,
                 u16* __restrict__ WTh, u16* __restrict__ WoTh,
                 u16* __restrict__ fmbtH, u16* __restrict__ fmbtL) {
  int bid = blockIdx.x;
  if (bid < 4096) {
    int gid = bid * 256 + threadIdx.x;
    int r = gid >> 8, u = gid & 255;
    const float* src = hs + (size_t)r * 2048 + u * 8;
    float4 v0 = *(const float4*)src, v1 = *(const float4*)(src + 4);
    float vals[8] = {v0.x, v0.y, v0.z, v0.w, v1.x, v1.y, v1.z, v1.w};
    u16x8 hv, lv;
    #pragma unroll
    for (int j = 0; j < 8; ++j) { u16 hh, ll; bf16_split(vals[j], hh, ll); hv[j] = hh; lv[j] = ll; }
    size_t off = ((size_t)(r >> 6) * 64 + (u >> 2)) * 2048
               + (size_t)((u >> 1) & 1) * 1024 + (size_t)((r >> 5) & 1) * 512
               + (size_t)(u & 1) * 256 + (size_t)(r & 31) * 8;
    *(u16x8*)(hsHt + off) = hv;
    *(u16x8*)(hsLt + off) = lv;
  } else if (bid < 5376) {
    int idx = bid - 4096;
    int P = idx >> 6, kt = idx & 63;
    const float* W; int Nsrc, n0;
    if (P < 16)      { W = Wq; Nsrc = 2048; n0 = P * 128; }
    else if (P < 18) { W = Wk; Nsrc = 256;  n0 = (P - 16) * 128; }
    else             { W = Wv; Nsrc = 256;  n0 = (P - 18) * 128; }
    wtrans_body(W, Nsrc, n0, WTh, P, kt);
  } else if (bid < 5504) {
    // fm B-frag tiling: per (h16, kt): 64 cols x 32 k -> 2048-u16 chunk.
    int idx = bid - 5376;                  // 0..127
    int h16 = idx >> 3, kt = idx & 7;
    const float* src = (h16 < 8) ? (fmq + (size_t)h16 * 16384)
                                 : (fmk + (size_t)(h16 - 8) * 16384);
    int t = threadIdx.x;
    int f = t & 63, kq = t >> 6;           // k = kq*8 + i
    u16x8 hv, lv;
    #pragma unroll
    for (int i = 0; i < 8; ++i) {
      float val = src[(size_t)(kt * 32 + kq * 8 + i) * 64 + f];
      u16 hh, ll; bf16_split(val, hh, ll); hv[i] = hh; lv[i] = ll;
    }
    size_t base = (size_t)(h16 * 8 + kt) * 2048 + (size_t)(kq >> 1) * 1024
                + (size_t)(f >> 5) * 512 + (size_t)(kq & 1) * 256
                + (size_t)(f & 31) * 8;
    *(u16x8*)(fmbtH + base) = hv;
    *(u16x8*)(fmbtL + base) = lv;
  } else {
    int idx = bid - 5504;
    wtrans_body(Wo, 2048, (idx >> 6) * 128, WoTh, idx >> 6, idx & 63);
  }
}

// Fallback standalone Wo tiling (small-workspace path).
__global__ __launch_bounds__(256)
void wtrans_wo(const float* __restrict__ Wo, u16* __restrict__ WoTh) {
  wtrans_body(Wo, 2048, blockIdx.x * 128, WoTh, blockIdx.x, blockIdx.y);
}

// Standalone prep_v (fallback path; bigws fuses into mfma_hh).
__global__ __launch_bounds__(256)
void prep_v(const float* __restrict__ v, u16* __restrict__ vbH,
            u16* __restrict__ vbL) {
  int bn = blockIdx.x;
  const float* vp = v + (size_t)bn * 64 * HD_;
  size_t cbout = (size_t)bn * 16384;
  int d = threadIdx.x;
  #pragma unroll
  for (int it = 0; it < 8; ++it) {
    int j0 = it * 8;
    u16x8 hv, lv;
    #pragma unroll
    for (int c = 0; c < 8; ++c) {
      u16 hh, ll; bf16_split(vp[(size_t)(j0 + c) * HD_ + d], hh, ll);
      hv[c] = hh; lv[c] = ll;
    }
    size_t off = cbout + vb_off(d, j0);
    *(u16x8*)(vbH + off) = hv;
    *(u16x8*)(vbL + off) = lv;
  }
}

// ---------------------------------------------------------------------------
// OLD 2-pass split-bf16 MFMA GEMM (64x128 tile, BK=32, 128 threads).
// Kept for the small k/v projection (full 256-block grid; R6-verified).
// ---------------------------------------------------------------------------
__device__ __forceinline__ void mfma_body(
    const u16* __restrict__ AtH, const u16* __restrict__ AtL,
    const u16* __restrict__ Bt, float* __restrict__ C, int cstride,
    int bm, int bn) {
  __shared__ __align__(16) u16 AsH[2048];
  __shared__ __align__(16) u16 AsL[2048];
  __shared__ __align__(16) u16 Bs[4096];
  const int t = threadIdx.x, lane = t & 63, wv = t >> 6;
  const u16* aSrc = (wv ? AtL : AtH) + (size_t)bm * 131072 + lane * 8;
  const u16* bSrc = Bt + (size_t)bn * 262144 + wv * 2048 + lane * 8;
  u16* aDst = wv ? AsL : AsH;
  u16* bDst = Bs + wv * 2048;

  f32x16 acc[2][2];
  #pragma unroll
  for (int a = 0; a < 2; ++a)
    #pragma unroll
    for (int b2 = 0; b2 < 2; ++b2)
      #pragma unroll
      for (int r = 0; r < 16; ++r) acc[a][b2][r] = 0.f;

  for (int kt = 0; kt < 64; ++kt) {
    const u16* ak = aSrc + (size_t)kt * 2048;
    const u16* bk = bSrc + (size_t)kt * 4096;
    __syncthreads();
    #pragma unroll
    for (int c = 0; c < 4; ++c) {
      gl_lds16(ak + c * 512, aDst + c * 512);
      gl_lds16(bk + c * 512, bDst + c * 512);
    }
    __syncthreads();

    #pragma unroll
    for (int ks = 0; ks < 2; ++ks) {
      const u16* ph = AsH + ks * 1024 + lane * 8;
      const u16* pl = AsL + ks * 1024 + lane * 8;
      const u16* pb = Bs + wv * 2048 + ks * 1024 + lane * 8;
      bf16x8 a0 = *(const bf16x8*)ph;
      bf16x8 a1 = *(const bf16x8*)(ph + 512);
      bf16x8 b0 = *(const bf16x8*)pb;
      bf16x8 b1 = *(const bf16x8*)(pb + 512);
      acc[0][0] = __builtin_amdgcn_mfma_f32_32x32x16_bf16(a0, b0, acc[0][0], 0, 0, 0);
      acc[0][1] = __builtin_amdgcn_mfma_f32_32x32x16_bf16(a0, b1, acc[0][1], 0, 0, 0);
      acc[1][0] = __builtin_amdgcn_mfma_f32_32x32x16_bf16(a1, b0, acc[1][0], 0, 0, 0);
      acc[1][1] = __builtin_amdgcn_mfma_f32_32x32x16_bf16(a1, b1, acc[1][1], 0, 0, 0);
      bf16x8 l0 = *(const bf16x8*)pl;
      bf16x8 l1 = *(const bf16x8*)(pl + 512);
      acc[0][0] = __builtin_amdgcn_mfma_f32_32x32x16_bf16(l0, b0, acc[0][0], 0, 0, 0);
      acc[0][1] = __builtin_amdgcn_mfma_f32_32x32x16_bf16(l0, b1, acc[0][1], 0, 0, 0);
      acc[1][0] = __builtin_amdgcn_mfma_f32_32x32x16_bf16(l1, b0, acc[1][0], 0, 0, 0);
      acc[1][1] = __builtin_amdgcn_mfma_f32_32x32x16_bf16(l1, b1, acc[1][1], 0, 0, 0);
    }
  }

  const int fr = lane & 31, g = lane >> 5;
  float* Cp = C + (size_t)(bm * 64) * cstride + wv * 64;
  #pragma unroll
  for (int mt = 0; mt < 2; ++mt)
    #pragma unroll
    for (int nt = 0; nt < 2; ++nt) {
      #pragma unroll
      for (int r = 0; r < 16; ++r) {
        int row = mt * 32 + (r & 3) + 8 * (r >> 2) + 4 * g;
        Cp[(size_t)row * cstride + nt * 32 + fr] = acc[mt][nt][r];
      }
    }
}

// ---------------------------------------------------------------------------
// Pipelined body v3: 128x128 tile, 4 waves, BK=32, triple ring (72 KB ->
// 2 blocks/CU), phase-split + counted vmcnt(6) + setprio. (R9: 68us, 44%.)
// ---------------------------------------------------------------------------
#define SUB_ 12288
#define MFB(a_, b_, c_) (c_) = __builtin_amdgcn_mfma_f32_32x32x16_bf16((a_), (b_), (c_), 0, 0, 0)

__device__ __forceinline__ void mfma_big_body(
    const u16* __restrict__ AtH, const u16* __restrict__ AtL,
    const u16* __restrict__ Bt, float* __restrict__ C, int cstride,
    int bm, int bn) {
  __shared__ __align__(16) u16 lds[3 * SUB_];
  const int t = threadIdx.x, lane = t & 63, wv = t >> 6;
  const int wm = wv >> 1, wn = wv & 1;

  const u16* gs[6];
  unsigned lo[6], gst[6];
  #pragma unroll
  for (int j = 0; j < 6; ++j) {
    int line = wv * 6 + j;
    if (line < 8) {
      gs[j] = AtH + ((size_t)(2 * bm + (line >> 2)) * 64) * 2048
                  + (size_t)(line & 3) * 512 + lane * 8;
      gst[j] = 2048;
    } else if (line < 16) {
      int l2 = line - 8;
      gs[j] = AtL + ((size_t)(2 * bm + (l2 >> 2)) * 64) * 2048
                  + (size_t)(l2 & 3) * 512 + lane * 8;
      gst[j] = 2048;
    } else {
      int l3 = line - 16;
      gs[j] = Bt + (size_t)bn * 262144 + (size_t)l3 * 512 + lane * 8;
      gst[j] = 4096;
    }
    lo[j] = line * 512;
  }

  f32x16 acc[2][2];
  #pragma unroll
  for (int a = 0; a < 2; ++a)
    #pragma unroll
    for (int b2 = 0; b2 < 2; ++b2)
      #pragma unroll
      for (int r = 0; r < 16; ++r) acc[a][b2][r] = 0.f;

  #pragma unroll
  for (int j = 0; j < 6; ++j) gl_lds16(gs[j], lds + lo[j]);
  #pragma unroll
  for (int j = 0; j < 6; ++j) gl_lds16(gs[j] + gst[j], lds + SUB_ + lo[j]);
  asm volatile("s_waitcnt vmcnt(6)" ::: "memory");
  __builtin_amdgcn_s_barrier();
  __builtin_amdgcn_sched_barrier(0);

  int cb = 0;
  for (int kt = 0; kt < 64; ++kt) {
    int sb = cb + 2 * SUB_; if (sb >= 3 * SUB_) sb -= 3 * SUB_;
    const u16* base = lds + cb;
    const u16* ph0 = base + wm * 2048 + lane * 8;
    const u16* pb0 = base + 8192 + wn * 2048 + lane * 8;

    bf16x8 a0 = *(const bf16x8*)(ph0);
    bf16x8 a1 = *(const bf16x8*)(ph0 + 512);
    bf16x8 l0 = *(const bf16x8*)(ph0 + 4096);
    bf16x8 l1 = *(const bf16x8*)(ph0 + 4608);
    bf16x8 b0 = *(const bf16x8*)(pb0);
    bf16x8 b1 = *(const bf16x8*)(pb0 + 512);
    if (kt < 62) {
      gl_lds16(gs[0] + (size_t)(kt + 2) * gst[0], lds + sb + lo[0]);
      gl_lds16(gs[1] + (size_t)(kt + 2) * gst[1], lds + sb + lo[1]);
      gl_lds16(gs[2] + (size_t)(kt + 2) * gst[2], lds + sb + lo[2]);
    }
    __builtin_amdgcn_s_barrier();
    asm volatile("s_waitcnt lgkmcnt(0)" ::: "memory");
    __builtin_amdgcn_sched_barrier(0);
    __builtin_amdgcn_s_setprio(1);
    MFB(a0, b0, acc[0][0]); MFB(a0, b1, acc[0][1]);
    MFB(a1, b0, acc[1][0]); MFB(a1, b1, acc[1][1]);
    MFB(l0, b0, acc[0][0]); MFB(l0, b1, acc[0][1]);
    MFB(l1, b0, acc[1][0]); MFB(l1, b1, acc[1][1]);
    __builtin_amdgcn_s_setprio(0);
    __builtin_amdgcn_s_barrier();
    __builtin_amdgcn_sched_barrier(0);

    bf16x8 c0 = *(const bf16x8*)(ph0 + 1024);
    bf16x8 c1 = *(const bf16x8*)(ph0 + 1536);
    bf16x8 m0 = *(const bf16x8*)(ph0 + 5120);
    bf16x8 m1 = *(const bf16x8*)(ph0 + 5632);
    bf16x8 d0 = *(const bf16x8*)(pb0 + 1024);
    bf16x8 d1 = *(const bf16x8*)(pb0 + 1536);
    if (kt < 62) {
      gl_lds16(gs[3] + (size_t)(kt + 2) * gst[3], lds + sb + lo[3]);
      gl_lds16(gs[4] + (size_t)(kt + 2) * gst[4], lds + sb + lo[4]);
      gl_lds16(gs[5] + (size_t)(kt + 2) * gst[5], lds + sb + lo[5]);
    }
    __builtin_amdgcn_s_barrier();
    asm volatile("s_waitcnt lgkmcnt(0)" ::: "memory");
    __builtin_amdgcn_sched_barrier(0);
    __builtin_amdgcn_s_setprio(1);
    MFB(c0, d0, acc[0][0]); MFB(c0, d1, acc[0][1]);
    MFB(c1, d0, acc[1][0]); MFB(c1, d1, acc[1][1]);
    MFB(m0, d0, acc[0][0]); MFB(m0, d1, acc[0][1]);
    MFB(m1, d0, acc[1][0]); MFB(m1, d1, acc[1][1]);
    __builtin_amdgcn_s_setprio(0);
    if (kt < 62) asm volatile("s_waitcnt vmcnt(6)" ::: "memory");
    else         asm volatile("s_waitcnt vmcnt(0)" ::: "memory");
    __builtin_amdgcn_s_barrier();
    __builtin_amdgcn_sched_barrier(0);
    cb += SUB_; if (cb == 3 * SUB_) cb = 0;
  }

  const int fr = lane & 31, g = lane >> 5;
  float* Cp = C + (size_t)(bm * 128 + wm * 64) * cstride + wn * 64;
  #pragma unroll
  for (int mt = 0; mt < 2; ++mt)
    #pragma unroll
    for (int nt = 0; nt < 2; ++nt) {
      #pragma unroll
      for (int r = 0; r < 16; ++r) {
        int row = mt * 32 + (r & 3) + 8 * (r >> 2) + 4 * g;
        Cp[(size_t)row * cstride + nt * 32 + fr] = acc[mt][nt][r];
      }
    }
}

// q projection: grid (16,32) = 512 blocks = exactly 2/CU (R9-verified).
__global__ __launch_bounds__(256, 2)
void mfma_q(const u16* __restrict__ hsHt, const u16* __restrict__ hsLt,
            const u16* __restrict__ WTh, float* __restrict__ q) {
  mfma_big_body(hsHt, hsLt, WTh, q + blockIdx.x * 128, 2048,
                blockIdx.y, blockIdx.x);
}

// k/v projections: old body, grid (4,64) = 256 blocks (R6-verified).
__global__ __launch_bounds__(128, 4)
void mfma_kv(const u16* __restrict__ hsHt, const u16* __restrict__ hsLt,
             const u16* __restrict__ WTh,
             float* __restrict__ k, float* __restrict__ v) {
  int bn = blockIdx.x;
  float* Cb; int co;
  if (bn < 2) { Cb = k; co = bn * 128; }
  else        { Cb = v; co = (bn - 2) * 128; }
  mfma_body(hsHt, hsLt, WTh, Cb + co, 256, blockIdx.y, 16 + bn);
}

__global__ __launch_bounds__(256, 2)
void mfma_wo(const u16* __restrict__ oHt, const u16* __restrict__ oLt,
             const u16* __restrict__ WoTh, float* __restrict__ out) {
  mfma_big_body(oHt, oLt, WoTh, out + blockIdx.x * 128, 2048,
                blockIdx.y, blockIdx.x);
}

// ---------------------------------------------------------------------------
// mfma_hh: RoPE + hedgehog projection via MFMA. (R9-verified.)
// ---------------------------------------------------------------------------
__global__ __launch_bounds__(256, 1)
void mfma_hh(const float* __restrict__ q, const float* __restrict__ kx,
             const float* __restrict__ cosb, const float* __restrict__ sinb,
             const u16* __restrict__ fmbtH, const u16* __restrict__ fmbtL,
             float* __restrict__ qf, float* __restrict__ kf,
             const float* __restrict__ vsrc,
             u16* __restrict__ vbH, u16* __restrict__ vbL) {
  int bid = blockIdx.x;
  if (bid >= 512) {                     // fused prep_v (bigws path)
    int bn = bid - 512;
    const float* vp = vsrc + (size_t)bn * 64 * HD_;
    size_t cbout = (size_t)bn * 16384;
    int d = threadIdx.x;
    #pragma unroll
    for (int it = 0; it < 8; ++it) {
      int j0 = it * 8;
      u16x8 hv, lv;
      #pragma unroll
      for (int c = 0; c < 8; ++c) {
        u16 hh, ll; bf16_split(vp[(size_t)(j0 + c) * HD_ + d], hh, ll);
        hv[c] = hh; lv[c] = ll;
      }
      size_t off = cbout + vb_off(d, j0);
      *(u16x8*)(vbH + off) = hv;
      *(u16x8*)(vbL + off) = lv;
    }
    return;
  }
  __shared__ __align__(16) u16 xlds[65536];   // [kt][rt32][hl][1024]
  const int t = threadIdx.x;
  const int rt = bid & 31, h16 = bid >> 5;
  const int rowbase = rt * 128;
  const float* xsrc; size_t xstr;
  if (h16 < 8) { xsrc = q + (size_t)h16 * 256; xstr = 2048; }
  else         { xsrc = kx;                    xstr = 256; }

  // ---- stage: RoPE + split -> A-frag LDS ----
  for (int iter = 0; iter < 16; ++iter) {
    int flat = iter * 1024 + t * 4;          // 128 rows x 128 dd
    int r = flat >> 7, dd = flat & 127;
    int grow = rowbase + r;
    int l = grow & 2047;
    const float* xr = xsrc + (size_t)grow * xstr + dd;
    float4 x1 = *(const float4*)xr;
    float4 x2 = *(const float4*)(xr + 128);
    float4 c  = *(const float4*)(cosb + (size_t)l * 128 + dd);
    float4 s  = *(const float4*)(sinb + (size_t)l * 128 + dd);
    float lo4[4] = {x1.x*c.x - x2.x*s.x, x1.y*c.y - x2.y*s.y,
                    x1.z*c.z - x2.z*s.z, x1.w*c.w - x2.w*s.w};
    float hi4[4] = {x1.x*s.x + x2.x*c.x, x1.y*s.y + x2.y*c.y,
                    x1.z*s.z + x2.z*c.z, x1.w*s.w + x2.w*c.w};
    int rt32 = r >> 5, r5 = r & 31;
    #pragma unroll
    for (int half = 0; half < 2; ++half) {
      int d = dd + half * 128;
      int kt = d >> 5, k = d & 31;
      unsigned base = (unsigned)((kt * 4 + rt32) * 2) * 1024
                    + (unsigned)(k >> 4) * 512 + (unsigned)((k >> 3) & 1) * 256
                    + (unsigned)r5 * 8 + (unsigned)(k & 7);
      const float* vv = half ? hi4 : lo4;
      u16x4 hv, lv;
      #pragma unroll
      for (int j = 0; j < 4; ++j) {
        u16 hh, ll; bf16_split(vv[j], hh, ll); hv[j] = hh; lv[j] = ll;
      }
      *(u16x4*)(xlds + base) = hv;
      *(u16x4*)(xlds + 1024 + base) = lv;
    }
  }
  __syncthreads();

  // ---- MFMA: wave w = rowtile, both nt; 3-pass split ----
  const int w = t >> 6, lane = t & 63;
  f32x16 acc[2];
  #pragma unroll
  for (int nt = 0; nt < 2; ++nt)
    #pragma unroll
    for (int r = 0; r < 16; ++r) acc[nt][r] = 0.f;

  const u16* fmbH = fmbtH + (size_t)h16 * 8 * 2048;
  const u16* fmbL = fmbtL + (size_t)h16 * 8 * 2048;
  #pragma unroll
  for (int kt = 0; kt < 8; ++kt) {
    unsigned xb = (unsigned)((kt * 4 + w) * 2) * 1024;
    #pragma unroll
    for (int ks = 0; ks < 2; ++ks) {
      bf16x8 xh = *(const bf16x8*)(xlds + xb + ks * 512 + lane * 8);
      bf16x8 xl = *(const bf16x8*)(xlds + xb + 1024 + ks * 512 + lane * 8);
      #pragma unroll
      for (int nt = 0; nt < 2; ++nt) {
        size_t fb = (size_t)kt * 2048 + ks * 1024 + nt * 512 + lane * 8;
        bf16x8 bh_ = *(const bf16x8*)((const short*)(fmbH + fb));
        bf16x8 bl_ = *(const bf16x8*)((const short*)(fmbL + fb));
        MFB(xh, bh_, acc[nt]); MFB(xl, bh_, acc[nt]); MFB(xh, bl_, acc[nt]);
      }
    }
  }

  // ---- softmax over concat(p,-p) + store qf/kf ----
  const int g = lane >> 5, f31 = lane & 31;
  float* outp = (h16 < 8) ? qf : kf;
  const int hh = h16 & 7;
  #pragma unroll
  for (int r = 0; r < 16; ++r) {
    int rowl = (r & 3) + 8 * (r >> 2) + 4 * g;
    int grow = rowbase + w * 32 + rowl;
    float p0 = acc[0][r], p1 = acc[1][r];
    float m = fmaxf(fabsf(p0), fabsf(p1));
    #pragma unroll
    for (int off = 16; off > 0; off >>= 1) m = fmaxf(m, __shfl_xor(m, off, 64));
    float e0 = __expf(p0 - m),  e0n = __expf(-p0 - m);
    float e1 = __expf(p1 - m),  e1n = __expf(-p1 - m);
    float zl = e0 + e0n + e1 + e1n;
    #pragma unroll
    for (int off = 16; off > 0; off >>= 1) zl += __shfl_xor(zl, off, 64);
    float inv = 1.0f / zl;
    int b = grow >> 11, l = grow & 2047;
    size_t ob = ((size_t)((b * 8 + hh) * 2048 + l)) * 128;
    outp[ob + f31]       = e0 * inv;
    outp[ob + 32 + f31]  = e1 * inv;
    outp[ob + 64 + f31]  = e0n * inv;
    outp[ob + 96 + f31]  = e1n * inv;
  }
}

// ---------------------------------------------------------------------------
// Phase A (MFMA rewrite): per-chunk kv[f][d] = sum_j kf[j][f] v[j][d]
// = (kf^T) . v -- A = kf^T frags (staged in LDS, split), B = pre-tiled vb
// frags (x=d, k=j; same mapping chunk_attn uses). Replaces the VALU-bound
// chunk_kv (~8.6e9 fp32 FLOP on the vector ALU). Block = one (bh, n) chunk,
// 4 waves = 4 f-tiles, each looping 8 d-tiles. 3-pass split like chunk_attn.
// Epilogue: shfl_xor(32) pairs g=0/g=1 rows into full octets -> coalesced
// u16x8 writes (g0 -> kvbH, g1 -> kvbL). Grid 512 = 2 blocks/CU.
// ---------------------------------------------------------------------------
__global__ __launch_bounds__(256, 2)
void chunk_kv_mfma(const float* __restrict__ kf,
                   const u16* __restrict__ vbH, const u16* __restrict__ vbL,
                   u16* __restrict__ kvbH, u16* __restrict__ kvbL) {
  __shared__ __align__(16) u16 kfA[16384];   // H [0,8192) | L [8192,16384)
  const int n = blockIdx.x & (NC_ - 1), bh = blockIdx.x >> 5;
  const int b = bh >> 3;
  const int t = threadIdx.x;

  // ---- stage kf^T A-frags: element (x=f row, k=j) = kf[j][f] ----
  {
    const float* kfp = kf + ((size_t)bh * L_ + (size_t)n * 64) * F_;
    int f = t & 127, jb = (t >> 7) * 32;
    int ft = f >> 5, frow = f & 31;
    #pragma unroll
    for (int jj = 0; jj < 32; ++jj) {
      int j = jb + jj;
      float val = kfp[(size_t)j * F_ + f];
      u16 hh, ll; bf16_split(val, hh, ll);
      int idx = ft * 2048 + (j >> 4) * 512 + ((j >> 3) & 1) * 256
              + frow * 8 + (j & 7);
      kfA[idx] = hh;
      kfA[8192 + idx] = ll;
    }
  }
  __syncthreads();

  const int w = t >> 6, lane = t & 63, g = lane >> 5, d31 = lane & 31;
  size_t vcb = ((size_t)(b * NC_ + n)) * 16384;
  size_t cb = (size_t)blockIdx.x * 32768;

  // preload this wave's f-tile A-frags (4 k-slices, H & L)
  bf16x8 ah[4], al[4];
  #pragma unroll
  for (int ks = 0; ks < 4; ++ks) {
    ah[ks] = *(const bf16x8*)(kfA + w * 2048 + ks * 512 + lane * 8);
    al[ks] = *(const bf16x8*)(kfA + 8192 + w * 2048 + ks * 512 + lane * 8);
  }

  #pragma unroll
  for (int dt = 0; dt < 8; ++dt) {
    f32x16 acc;
    #pragma unroll
    for (int r = 0; r < 16; ++r) acc[r] = 0.f;
    #pragma unroll
    for (int ks = 0; ks < 4; ++ks) {
      size_t bv = vcb + vb_off(dt * 32, ks * 16) + lane * 8;
      bf16x8 bhv = *(const bf16x8*)((const short*)(vbH + bv));
      bf16x8 blv = *(const bf16x8*)((const short*)(vbL + bv));
      MFB(ah[ks], bhv, acc); MFB(al[ks], bhv, acc); MFB(ah[ks], blv, acc);
    }
    // epilogue: rows f = w*32 + (r&3)+8*(r>>2)+4g, col d = dt*32 + d31.
    // Quad q (regs 4q..4q+3) covers f&7 = {0..3}+4g at f>>3 = q; pair with
    // lane^32 (same d, other g) to build the full octet.
    int d = dt * 32 + d31;
    #pragma unroll
    for (int qd = 0; qd < 4; ++qd) {
      float vals[8];
      #pragma unroll
      for (int c = 0; c < 4; ++c) {
        float mine = acc[qd * 4 + c];
        float other = __shfl_xor(mine, 32, 64);
        vals[c]     = g ? other : mine;
        vals[c + 4] = g ? mine : other;
      }
      u16x8 hv, lv;
      #pragma unroll
      for (int c = 0; c < 8; ++c) {
        u16 hh, ll; bf16_split(vals[c], hh, ll); hv[c] = hh; lv[c] = ll;
      }
      size_t off8 = cb + kvb_off(d, w * 32 + qd * 8);
      if (g == 0) *(u16x8*)(kvbH + off8) = hv;
      else        *(u16x8*)(kvbL + off8) = lv;
    }
  }
}

// Phase B: in-place exclusive prefix over the 32 chunks, on split bf16.
__global__ __launch_bounds__(256)
void chunk_scan_kernel(u16* __restrict__ kvbH, u16* __restrict__ kvbL) {
  int bh = blockIdx.x >> 4, g = blockIdx.x & 15;
  int d = threadIdx.x;
  size_t off = kvb_off(d, g * 8);
  float run[8] = {0.f, 0.f, 0.f, 0.f, 0.f, 0.f, 0.f, 0.f};
  for (int n = 0; n < NC_; ++n) {
    size_t a = ((size_t)(bh * 32 + n)) * 32768 + off;
    u16x8 hv = *(u16x8*)(kvbH + a);
    u16x8 lv = *(u16x8*)(kvbL + a);
    u16x8 oh, ol;
    #pragma unroll
    for (int c = 0; c < 8; ++c) {
      float val = __uint_as_float((unsigned)hv[c] << 16)
                + __uint_as_float((unsigned)lv[c] << 16);
      u16 hh, ll; bf16_split(run[c], hh, ll); oh[c] = hh; ol[c] = ll;
      run[c] += val;
    }
    *(u16x8*)(kvbH + a) = oh;
    *(u16x8*)(kvbL + a) = ol;
  }
}

// ---------------------------------------------------------------------------
// Phase C (MFMA): epilogue writes A-tiled split bf16 oHt/oLt directly.
// ---------------------------------------------------------------------------
__global__ __launch_bounds__(256, 2)
void chunk_attn_kernel(const float* __restrict__ qf, const float* __restrict__ kf,
                       const u16* __restrict__ vbH, const u16* __restrict__ vbL,
                       const u16* __restrict__ kvbH, const u16* __restrict__ kvbL,
                       u16* __restrict__ oHt, u16* __restrict__ oLt) {
  __shared__ __align__(16) u16 lds[32768];   // qsH|qsL|kfH|kfL
  const int n = blockIdx.x & (NC_ - 1), bh = blockIdx.x >> 5;
  const int h = bh & 7, b = bh >> 3;
  const int t = threadIdx.x;
  const int w = t >> 6, i31 = t & 31, G = (t >> 5) & 1;
  const int l8 = (t & 63) * 8;

  {
    const float* qp = qf + ((size_t)bh * L_ + (size_t)n * 64) * F_;
    const float* kp = kf + ((size_t)bh * L_ + (size_t)n * 64) * F_;
    int o8 = t & 15, ib = t >> 4;
    #pragma unroll
    for (int iter = 0; iter < 4; ++iter) {
      int i = ib + iter * 16;
      int it = i >> 5, ks = o8 >> 1;
      int sub = (it * 8 + ks) * 512 + (o8 & 1) * 256 + (i & 31) * 8;
      {
        const float* src = qp + (size_t)i * 128 + o8 * 8;
        float4 a = *(const float4*)src, c = *(const float4*)(src + 4);
        float vals[8] = {a.x, a.y, a.z, a.w, c.x, c.y, c.z, c.w};
        u16x8 hv, lv;
        #pragma unroll
        for (int j = 0; j < 8; ++j) {
          u16 hh, ll; bf16_split(vals[j] * SCALE_Q, hh, ll);
          hv[j] = hh; lv[j] = ll;
        }
        *(u16x8*)(lds + sub) = hv;
        *(u16x8*)(lds + 8192 + sub) = lv;
      }
      {
        const float* src = kp + (size_t)i * 128 + o8 * 8;
        float4 a = *(const float4*)src, c = *(const float4*)(src + 4);
        float vals[8] = {a.x, a.y, a.z, a.w, c.x, c.y, c.z, c.w};
        u16x8 hv, lv;
        #pragma unroll
        for (int j = 0; j < 8; ++j) {
          u16 hh, ll; bf16_split(vals[j], hh, ll);
          hv[j] = hh; lv[j] = ll;
        }
        *(u16x8*)(lds + 16384 + sub) = hv;
        *(u16x8*)(lds + 24576 + sub) = lv;
      }
    }
  }
  __syncthreads();

  const u16* Lq  = lds;
  const u16* Lql = lds + 8192;
  const u16* Lk  = lds + 16384;
  const u16* Lkl = lds + 24576;

  // ---- phase S: sT = kf · qs^T (3-pass split) ----
  f32x16 st[2][2];
  #pragma unroll
  for (int a = 0; a < 2; ++a)
    #pragma unroll
    for (int c = 0; c < 2; ++c)
      #pragma unroll
      for (int r = 0; r < 16; ++r) st[a][c][r] = 0.f;

  #pragma unroll
  for (int ks = 0; ks < 8; ++ks) {
    bf16x8 kh0 = *(const bf16x8*)(Lk  + ks * 512 + l8);
    bf16x8 kh1 = *(const bf16x8*)(Lk  + (8 + ks) * 512 + l8);
    bf16x8 kl0 = *(const bf16x8*)(Lkl + ks * 512 + l8);
    bf16x8 kl1 = *(const bf16x8*)(Lkl + (8 + ks) * 512 + l8);
    bf16x8 qh0 = *(const bf16x8*)(Lq  + ks * 512 + l8);
    bf16x8 qh1 = *(const bf16x8*)(Lq  + (8 + ks) * 512 + l8);
    bf16x8 ql0 = *(const bf16x8*)(Lql + ks * 512 + l8);
    bf16x8 ql1 = *(const bf16x8*)(Lql + (8 + ks) * 512 + l8);
    MFB(kh0, qh0, st[0][0]); MFB(kh0, ql0, st[0][0]); MFB(kl0, qh0, st[0][0]);
    MFB(kh0, qh1, st[0][1]); MFB(kh0, ql1, st[0][1]); MFB(kl0, qh1, st[0][1]);
    MFB(kh1, qh0, st[1][0]); MFB(kh1, ql0, st[1][0]); MFB(kl1, qh0, st[1][0]);
    MFB(kh1, qh1, st[1][1]); MFB(kh1, ql1, st[1][1]); MFB(kl1, qh1, st[1][1]);
  }

  // ---- mask + split + cross-lane transpose: sT C-regs -> s A-frags ----
  bf16x8 sfH[2][4], sfL[2][4];
  #pragma unroll
  for (int mt = 0; mt < 2; ++mt) {
    int iv = mt * 32 + i31;
    #pragma unroll
    for (int ksj = 0; ksj < 4; ++ksj) {
      const int jt = ksj >> 1, kb = ksj & 1;
      unsigned ph[4], pl[4];
      #pragma unroll
      for (int half = 0; half < 2; ++half) {
        u16 hh[4], ll[4];
        #pragma unroll
        for (int c = 0; c < 4; ++c) {
          int r = 8 * kb + 4 * half + c;
          int jv = jt * 32 + (r & 3) + 8 * (r >> 2) + 4 * G;
          float mv = (jv <= iv) ? st[jt][mt][r] : 0.f;
          u16 h_, l_; bf16_split(mv, h_, l_);
          hh[c] = h_; ll[c] = l_;
        }
        ph[half * 2 + 0] = (unsigned)hh[0] | ((unsigned)hh[1] << 16);
        ph[half * 2 + 1] = (unsigned)hh[2] | ((unsigned)hh[3] << 16);
        pl[half * 2 + 0] = (unsigned)ll[0] | ((unsigned)ll[1] << 16);
        pl[half * 2 + 1] = (unsigned)ll[2] | ((unsigned)ll[3] << 16);
      }
      unsigned rH1 = (unsigned)__shfl_xor((int)(G ? ph[0] : ph[2]), 32, 64);
      unsigned rH2 = (unsigned)__shfl_xor((int)(G ? ph[1] : ph[3]), 32, 64);
      unsigned rL1 = (unsigned)__shfl_xor((int)(G ? pl[0] : pl[2]), 32, 64);
      unsigned rL2 = (unsigned)__shfl_xor((int)(G ? pl[1] : pl[3]), 32, 64);
      u32x4 wH, wL;
      wH[0] = G ? rH1 : ph[0]; wH[1] = G ? rH2 : ph[1];
      wH[2] = G ? ph[2] : rH1; wH[3] = G ? ph[3] : rH2;
      wL[0] = G ? rL1 : pl[0]; wL[1] = G ? rL2 : pl[1];
      wL[2] = G ? pl[2] : rL1; wL[3] = G ? pl[3] : rL2;
      sfH[mt][ksj] = __builtin_bit_cast(bf16x8, wH);
      sfL[mt][ksj] = __builtin_bit_cast(bf16x8, wL);
    }
  }

  f32x16 acc[2][2];
  #pragma unroll
  for (int a = 0; a < 2; ++a)
    #pragma unroll
    for (int c = 0; c < 2; ++c)
      #pragma unroll
      for (int r = 0; r < 16; ++r) acc[a][c][r] = 0.f;

  // ---- phase A (intra): acc += s · v, v frags pre-tiled ----
  {
    size_t vcb = ((size_t)(b * NC_ + n)) * 16384;
    #pragma unroll
    for (int nt = 0; nt < 2; ++nt) {
      #pragma unroll
      for (int ksj = 0; ksj < 4; ++ksj) {
        size_t basev = vcb + vb_off(w * 64 + nt * 32, ksj * 16) + l8;
        bf16x8 vH = *(const bf16x8*)((const short*)(vbH + basev));
        bf16x8 vL = *(const bf16x8*)((const short*)(vbL + basev));
        MFB(sfH[0][ksj], vH, acc[0][nt]); MFB(sfL[0][ksj], vH, acc[0][nt]);
        MFB(sfH[0][ksj], vL, acc[0][nt]);
        MFB(sfH[1][ksj], vH, acc[1][nt]); MFB(sfL[1][ksj], vH, acc[1][nt]);
        MFB(sfH[1][ksj], vL, acc[1][nt]);
      }
    }
  }

  // ---- phase I (inter): acc += qs · kv_cum ----
  {
    size_t cb = (size_t)blockIdx.x * 32768;
    #pragma unroll
    for (int ks = 0; ks < 8; ++ks) {
      bf16x8 qa_h0 = *(const bf16x8*)(Lq  + ks * 512 + l8);
      bf16x8 qa_h1 = *(const bf16x8*)(Lq  + (8 + ks) * 512 + l8);
      bf16x8 qa_l0 = *(const bf16x8*)(Lql + ks * 512 + l8);
      bf16x8 qa_l1 = *(const bf16x8*)(Lql + (8 + ks) * 512 + l8);
      #pragma unroll
      for (int nt = 0; nt < 2; ++nt) {
        size_t base = cb + kvb_off(w * 64 + nt * 32, ks * 16) + l8;
        bf16x8 kvH = *(const bf16x8*)((const short*)(kvbH + base));
        bf16x8 kvL = *(const bf16x8*)((const short*)(kvbL + base));
        MFB(qa_h0, kvH, acc[0][nt]); MFB(qa_l0, kvH, acc[0][nt]);
        MFB(qa_h0, kvL, acc[0][nt]);
        MFB(qa_h1, kvH, acc[1][nt]); MFB(qa_l1, kvH, acc[1][nt]);
        MFB(qa_h1, kvL, acc[1][nt]);
      }
    }
  }

  // ---- fused epilogue: A-tiled split bf16 write ----
  {
    int p = b * NC_ + n;
    #pragma unroll
    for (int mt = 0; mt < 2; ++mt)
      #pragma unroll
      for (int nt = 0; nt < 2; ++nt) {
        int u_ = h * 32 + w * 8 + nt * 4 + (i31 >> 3);
        size_t ob = ((size_t)p * 64 + (u_ >> 2)) * 2048
                  + (size_t)((u_ >> 1) & 1) * 1024 + (size_t)mt * 512
                  + (size_t)(u_ & 1) * 256 + (size_t)(i31 & 7);
        #pragma unroll
        for (int r = 0; r < 16; ++r) {
          int rr = (r & 3) + 8 * (r >> 2) + 4 * G;
          u16 hh, ll; bf16_split(acc[mt][nt][r], hh, ll);
          oHt[ob + (size_t)rr * 8] = hh;
          oLt[ob + (size_t)rr * 8] = ll;
        }
      }
  }
}

// ---------------------------------------------------------------------------
extern "C" void kernel_launch(void* const* d_in, const int* in_sizes, int n_in,
                              void* d_out, int out_size, void* d_ws, size_t ws_size,
                              hipStream_t stream) {
  const float* hs   = (const float*)d_in[0];
  const float* fcos = (const float*)d_in[1];
  const float* fsin = (const float*)d_in[2];
  // d_in[3] = mask (all ones, unused)
  const float* Wq  = (const float*)d_in[4];
  const float* Wk  = (const float*)d_in[5];
  const float* Wv  = (const float*)d_in[6];
  const float* Wo  = (const float*)d_in[7];
  const float* fmq = (const float*)d_in[8];
  const float* fmk = (const float*)d_in[9];
  float* out = (float*)d_out;

  float* ws = (float*)d_ws;
  float* q  = ws;                                   // 32MB; later oHt/oLt
  float* k  = q  + (size_t)M_ * 2048;               // 4MB; (!bigws: vb tiles)
  float* v  = k  + (size_t)M_ * 256;                // 4MB
  float* qf = v  + (size_t)M_ * 256;                // 16MB
  float* kf = qf + (size_t)B_ * H_ * L_ * F_;       // 16MB
  float* kvr = kf + (size_t)B_ * H_ * L_ * F_;      // 64MB region

  u16* hsHt = (u16*)kvr;                      // 16 MB
  u16* hsLt = hsHt + (size_t)M_ * 2048;       // 16 MB
  u16* WTh  = hsLt + (size_t)M_ * 2048;       // 10 MB
  // fm B-frag tiles in the dead tail of kvr (live until mfma_hh; kvb
  // overwrites kvr only later, in chunk_kv_mfma).
  u16* fmbtH = WTh + (size_t)1280 * 4096;     // 0.5 MB
  u16* fmbtL = fmbtH + (size_t)131072 * 2;    // 0.5 MB
  u16* kvbH = (u16*)kvr;                      // 32 MB
  u16* kvbL = kvbH + (size_t)512 * 32768;     // 32 MB
  u16* oHt  = (u16*)q;                        // 16 MB (q dead after mfma_hh)
  u16* oLt  = oHt + (size_t)M_ * 2048;        // 16 MB

  // bigws extras past the 136 MB base: WoTh (8 MB) + vb tiles (4 MB).
  const size_t WS_BASE = (size_t)142606336;   // 136 MB
  bool bigws = ws_size >= WS_BASE + (size_t)12582912;
  u16* WoTh = bigws ? (u16*)((char*)d_ws + WS_BASE) : (u16*)kvr;
  u16* vbH  = bigws ? (u16*)((char*)d_ws + WS_BASE + 8388608) : (u16*)k;
  u16* vbL  = vbH + (size_t)64 * 16384;

  // 1) Fused prep: hs split + Wq/Wk/Wv tiling + fm tiling (+ Wo when bigws)
  prep_kernel<<<bigws ? 6528 : 5504, 256, 0, stream>>>(
      hs, Wq, Wk, Wv, Wo, fmq, fmk, hsHt, hsLt, WTh, WoTh, fmbtH, fmbtL);
  // 2a) q projection: pipelined body, grid (16,32) = 512 blocks = 2/CU exact
  mfma_q<<<dim3(16, 32), 256, 0, stream>>>(hsHt, hsLt, WTh, q);
  // 2b) k/v projections: old body, 256 blocks
  mfma_kv<<<dim3(4, 64), 128, 0, stream>>>(hsHt, hsLt, WTh, k, v);
  // 3) MFMA RoPE+hedgehog; bigws fuses prep_v
  mfma_hh<<<bigws ? 576 : 512, 256, 0, stream>>>(
      q, k, fcos, fsin, fmbtH, fmbtL, qf, kf, v, vbH, vbL);
  // 3b) fallback prep_v AFTER mfma_hh (k fp32 dead -> no race)
  if (!bigws)
    prep_v<<<B_ * NC_, 256, 0, stream>>>(v, vbH, vbL);
  // 4) Per-chunk kv outer products via MFMA (kf^T x vb frags) + in-place scan
  chunk_kv_mfma<<<B_ * H_ * NC_, 256, 0, stream>>>(kf, vbH, vbL, kvbH, kvbL);
  chunk_scan_kernel<<<256, 256, 0, stream>>>(kvbH, kvbL);
  // 5) MFMA inter+intra chunk attention -> A-tiled split bf16 (fused epilogue)
  chunk_attn_kernel<<<B_ * H_ * NC_, 256, 0, stream>>>(qf, kf, vbH, vbL,
                                                       kvbH, kvbL, oHt, oLt);
  // 6) Output projection (fallback path tiles Wo late)
  if (!bigws)
    wtrans_wo<<<dim3(16, 64), 256, 0, stream>>>(Wo, WoTh);
  mfma_wo<<<dim3(16, 32), 256, 0, stream>>>(oHt, oLt, WoTh, out);
}